// Round 1
// baseline (3042.815 us; speedup 1.0000x reference)
//
#include <hip/hip_runtime.h>
#include <math.h>

#define B_  2
#define S_  2048
#define DM_ 2048
#define H_  16
#define DK_ 128
#define M_  (B_ * S_)

// ---------------------------------------------------------------------------
// Generic fp32 GEMM: C[M x N] = A[M x K] @ B[K x N] + bias[N]
// 64x64 tile, BK=16, 256 threads, 4x4 acc per thread.
// LDS padded to 68 floats/row: keeps 16B alignment (272B rows) and spreads banks.
// ---------------------------------------------------------------------------
__global__ __launch_bounds__(256) void gemm_bias_k(
    const float* __restrict__ A, const float* __restrict__ Bm,
    const float* __restrict__ bias, float* __restrict__ C, int N, int K) {
  __shared__ float As[16][68];
  __shared__ float Bs[16][68];
  const int tid = threadIdx.x;
  const int tn = tid & 15, tm = tid >> 4;
  const int row0 = blockIdx.y * 64, col0 = blockIdx.x * 64;
  float acc[4][4] = {};

  for (int k0 = 0; k0 < K; k0 += 16) {
#pragma unroll
    for (int i = 0; i < 4; ++i) {
      int idx = tid + i * 256;
      int ar = idx >> 4, ak = idx & 15;
      As[ak][ar] = A[(size_t)(row0 + ar) * K + (k0 + ak)];
    }
#pragma unroll
    for (int i = 0; i < 4; ++i) {
      int idx = tid + i * 256;
      int br = idx >> 6, bc = idx & 63;
      Bs[br][bc] = Bm[(size_t)(k0 + br) * N + (col0 + bc)];
    }
    __syncthreads();
#pragma unroll
    for (int kk = 0; kk < 16; ++kk) {
      float4 a4 = *(const float4*)&As[kk][tm * 4];
      float4 b4 = *(const float4*)&Bs[kk][tn * 4];
      float av[4] = {a4.x, a4.y, a4.z, a4.w};
      float bv[4] = {b4.x, b4.y, b4.z, b4.w};
#pragma unroll
      for (int i = 0; i < 4; ++i)
#pragma unroll
        for (int j = 0; j < 4; ++j)
          acc[i][j] = fmaf(av[i], bv[j], acc[i][j]);
    }
    __syncthreads();
  }

  float4 bb = *(const float4*)&bias[col0 + tn * 4];
#pragma unroll
  for (int i = 0; i < 4; ++i) {
    int row = row0 + tm * 4 + i;
    float4 o;
    o.x = acc[i][0] + bb.x;
    o.y = acc[i][1] + bb.y;
    o.z = acc[i][2] + bb.z;
    o.w = acc[i][3] + bb.w;
    *(float4*)&C[(size_t)row * N + col0 + tn * 4] = o;
  }
}

// ---------------------------------------------------------------------------
// RoPE (in-place). Row width = pairs_per_row*2; head = 128 wide; pair i in
// head: (2i, 2i+1). inv_freq = 10000^(-2i/128) = exp2(-i * 2*log2(1e4)/128).
// ---------------------------------------------------------------------------
__global__ void rope_k(float* __restrict__ X, const int* __restrict__ pos,
                       int total, int pairs_per_row) {
  int idx = blockIdx.x * 256 + threadIdx.x;
  if (idx >= total) return;
  int row = idx / pairs_per_row;
  int rem = idx - row * pairs_per_row;
  int head = rem >> 6;
  int i = rem & 63;
  int s = row & (S_ - 1);
  float p = (float)pos[s];
  float inv_freq = exp2f((float)i * -0.2076205059304601f);  // -2*log2(1e4)/128
  float ang = p * inv_freq;
  float c, sn;
  sincosf(ang, &sn, &c);
  size_t base = (size_t)row * (size_t)(pairs_per_row * 2) + head * 128 + 2 * i;
  float x1 = X[base], x2 = X[base + 1];
  X[base]     = x1 * c - x2 * sn;
  X[base + 1] = x1 * sn + x2 * c;
}

// ---------------------------------------------------------------------------
// Causal MQA flash attention (fp32).
// Block = 256 threads handles one (b, h, 128-row Q tile).
// Thread pair (2r, 2r+1) owns Q row r; each thread owns 64 of the 128 dims.
// K/V staged per 64-row tile in LDS (64 KiB). Online softmax; wave-uniform
// early break on the causal tail.
// ---------------------------------------------------------------------------
__global__ __launch_bounds__(256) void attn_k(
    const float* __restrict__ Q, const float* __restrict__ K,
    const float* __restrict__ V, float* __restrict__ O) {
  __shared__ float Kt[64][128];
  __shared__ float Vt[64][128];
  const int qt = blockIdx.x, h = blockIdx.y, b = blockIdx.z;
  const int tid = threadIdx.x;
  const int r = tid >> 1, half = tid & 1;
  const int qrow = qt * 128 + r;
  const int wmaxrow = qt * 128 + ((tid >> 6) * 32 + 31);  // wave's max q row

  const float* qptr = Q + (size_t)(b * S_ + qrow) * DM_ + h * DK_ + half * 64;
  float qh[64];
#pragma unroll
  for (int d4 = 0; d4 < 16; ++d4) {
    float4 v = ((const float4*)qptr)[d4];
    qh[4 * d4 + 0] = v.x; qh[4 * d4 + 1] = v.y;
    qh[4 * d4 + 2] = v.z; qh[4 * d4 + 3] = v.w;
  }
  float acc[64];
#pragma unroll
  for (int d = 0; d < 64; ++d) acc[d] = 0.f;
  float m = -INFINITY, l = 0.f;

  const int kend = (qt + 1) * 128;
  for (int k0 = 0; k0 < kend; k0 += 64) {
    __syncthreads();
#pragma unroll
    for (int i = 0; i < 8; ++i) {
      int idx4 = tid + i * 256;          // 2048 float4s = 64x128 floats
      int row = idx4 >> 5, c4 = idx4 & 31;
      size_t g = (size_t)(b * S_ + k0 + row) * DK_;
      ((float4*)&Kt[row][0])[c4] = ((const float4*)(K + g))[c4];
      ((float4*)&Vt[row][0])[c4] = ((const float4*)(V + g))[c4];
    }
    __syncthreads();

#pragma unroll 1
    for (int j = 0; j < 64; ++j) {
      int kg = k0 + j;
      if (kg > wmaxrow) break;  // wave-uniform causal tail skip
      float part = 0.f;
      const float4* k4 = (const float4*)&Kt[j][half * 64];
#pragma unroll
      for (int d4 = 0; d4 < 16; ++d4) {
        float4 kv = k4[d4];
        part = fmaf(qh[4 * d4 + 0], kv.x, part);
        part = fmaf(qh[4 * d4 + 1], kv.y, part);
        part = fmaf(qh[4 * d4 + 2], kv.z, part);
        part = fmaf(qh[4 * d4 + 3], kv.w, part);
      }
      part += __shfl_xor(part, 1);  // merge the two halves of the dot
      bool ok = (kg <= qrow);
      float sc = ok ? part * 0.08838834764831845f : -INFINITY;  // 1/sqrt(128)
      float mn = fmaxf(m, sc);
      float corr = __expf(m - mn);   // first iter: exp(-inf)=0, acc/l are 0
      float p = ok ? __expf(sc - mn) : 0.f;
      l = l * corr + p;
      m = mn;
      const float4* v4 = (const float4*)&Vt[j][half * 64];
#pragma unroll
      for (int d4 = 0; d4 < 16; ++d4) {
        float4 vv = v4[d4];
        acc[4 * d4 + 0] = fmaf(p, vv.x, acc[4 * d4 + 0] * corr);
        acc[4 * d4 + 1] = fmaf(p, vv.y, acc[4 * d4 + 1] * corr);
        acc[4 * d4 + 2] = fmaf(p, vv.z, acc[4 * d4 + 2] * corr);
        acc[4 * d4 + 3] = fmaf(p, vv.w, acc[4 * d4 + 3] * corr);
      }
    }
  }

  float invl = 1.0f / l;
  float* optr = O + (size_t)(b * S_ + qrow) * DM_ + h * DK_ + half * 64;
#pragma unroll
  for (int d4 = 0; d4 < 16; ++d4) {
    float4 o;
    o.x = acc[4 * d4 + 0] * invl; o.y = acc[4 * d4 + 1] * invl;
    o.z = acc[4 * d4 + 2] * invl; o.w = acc[4 * d4 + 3] * invl;
    ((float4*)optr)[d4] = o;
  }
}

// ---------------------------------------------------------------------------
extern "C" void kernel_launch(void* const* d_in, const int* in_sizes, int n_in,
                              void* d_out, int out_size, void* d_ws,
                              size_t ws_size, hipStream_t stream) {
  const float* x  = (const float*)d_in[0];
  const int*   tp = (const int*)d_in[1];
  const float* Wq = (const float*)d_in[2];
  const float* bq = (const float*)d_in[3];
  const float* Wk = (const float*)d_in[4];
  const float* bk = (const float*)d_in[5];
  const float* Wv = (const float*)d_in[6];
  const float* bv = (const float*)d_in[7];
  const float* Wo = (const float*)d_in[8];
  const float* bo = (const float*)d_in[9];
  float* out = (float*)d_out;

  float* ws = (float*)d_ws;
  float* Qb = ws;                          // M_ * DM_  = 8,388,608 floats
  float* Kb = Qb + (size_t)M_ * DM_;       // M_ * DK_  =   524,288
  float* Vb = Kb + (size_t)M_ * DK_;       // M_ * DK_
  float* AT = Vb + (size_t)M_ * DK_;       // M_ * DM_

  // Projections
  gemm_bias_k<<<dim3(DM_ / 64, M_ / 64), 256, 0, stream>>>(x, Wq, bq, Qb, DM_, DM_);
  gemm_bias_k<<<dim3(DK_ / 64, M_ / 64), 256, 0, stream>>>(x, Wk, bk, Kb, DK_, DM_);
  gemm_bias_k<<<dim3(DK_ / 64, M_ / 64), 256, 0, stream>>>(x, Wv, bv, Vb, DK_, DM_);

  // RoPE on Q (16 heads) and K (1 head)
  {
    int total = M_ * (DM_ / 2);
    rope_k<<<(total + 255) / 256, 256, 0, stream>>>(Qb, tp, total, DM_ / 2);
  }
  {
    int total = M_ * (DK_ / 2);
    rope_k<<<(total + 255) / 256, 256, 0, stream>>>(Kb, tp, total, DK_ / 2);
  }

  // Causal MQA attention
  attn_k<<<dim3(S_ / 128, H_, B_), 256, 0, stream>>>(Qb, Kb, Vb, AT);

  // Output projection
  gemm_bias_k<<<dim3(DM_ / 64, M_ / 64), 256, 0, stream>>>(AT, Wo, bo, out, DM_, DM_);
}

// Round 2
// 1422.217 us; speedup vs baseline: 2.1395x; 2.1395x over previous
//
#include <hip/hip_runtime.h>
#include <math.h>

#define B_  2
#define S_  2048
#define DM_ 2048
#define H_  16
#define DK_ 128
#define M_  (B_ * S_)

typedef __attribute__((ext_vector_type(8))) short bf16x8;
typedef __attribute__((ext_vector_type(4))) float f32x4;
typedef unsigned short ushort_t;
typedef unsigned int uint_t;

__device__ inline ushort_t f2bf(float f) {
  union { float f; uint_t u; } v; v.f = f;
  uint_t u = v.u;
  uint_t r = (u + 0x7FFFu + ((u >> 16) & 1u)) >> 16;  // RNE
  return (ushort_t)r;
}

// ---------------------------------------------------------------------------
// fp32 GEMM: C[MxN] = A[MxK] @ B[KxN] + bias (fp32 out) — used for out-proj.
// ---------------------------------------------------------------------------
__global__ __launch_bounds__(256) void gemm_bias_k(
    const float* __restrict__ A, const float* __restrict__ Bm,
    const float* __restrict__ bias, float* __restrict__ C, int N, int K) {
  __shared__ float As[16][68];
  __shared__ float Bs[16][68];
  const int tid = threadIdx.x;
  const int tn = tid & 15, tm = tid >> 4;
  const int row0 = blockIdx.y * 64, col0 = blockIdx.x * 64;
  float acc[4][4] = {};

  for (int k0 = 0; k0 < K; k0 += 16) {
#pragma unroll
    for (int i = 0; i < 4; ++i) {
      int idx = tid + i * 256;
      int ar = idx >> 4, ak = idx & 15;
      As[ak][ar] = A[(size_t)(row0 + ar) * K + (k0 + ak)];
    }
#pragma unroll
    for (int i = 0; i < 4; ++i) {
      int idx = tid + i * 256;
      int br = idx >> 6, bc = idx & 63;
      Bs[br][bc] = Bm[(size_t)(k0 + br) * N + (col0 + bc)];
    }
    __syncthreads();
#pragma unroll
    for (int kk = 0; kk < 16; ++kk) {
      float4 a4 = *(const float4*)&As[kk][tm * 4];
      float4 b4 = *(const float4*)&Bs[kk][tn * 4];
      float av[4] = {a4.x, a4.y, a4.z, a4.w};
      float bv[4] = {b4.x, b4.y, b4.z, b4.w};
#pragma unroll
      for (int i = 0; i < 4; ++i)
#pragma unroll
        for (int j = 0; j < 4; ++j)
          acc[i][j] = fmaf(av[i], bv[j], acc[i][j]);
    }
    __syncthreads();
  }

  float4 bb = *(const float4*)&bias[col0 + tn * 4];
#pragma unroll
  for (int i = 0; i < 4; ++i) {
    int row = row0 + tm * 4 + i;
    float4 o;
    o.x = acc[i][0] + bb.x; o.y = acc[i][1] + bb.y;
    o.z = acc[i][2] + bb.z; o.w = acc[i][3] + bb.w;
    *(float4*)&C[(size_t)row * N + col0 + tn * 4] = o;
  }
}

// ---------------------------------------------------------------------------
// fp32 GEMM -> bf16 out, optional fused RoPE in the epilogue.
// Heads are 128 wide; pair i in head = cols (2i, 2i+1); pairs never straddle
// the 4-col group a thread owns.
// ---------------------------------------------------------------------------
template <bool DO_ROPE>
__global__ __launch_bounds__(256) void gemm_bias_bf16_k(
    const float* __restrict__ A, const float* __restrict__ Bm,
    const float* __restrict__ bias, const int* __restrict__ pos,
    ushort_t* __restrict__ C, int N, int K) {
  __shared__ float As[16][68];
  __shared__ float Bs[16][68];
  const int tid = threadIdx.x;
  const int tn = tid & 15, tm = tid >> 4;
  const int row0 = blockIdx.y * 64, col0 = blockIdx.x * 64;
  float acc[4][4] = {};

  for (int k0 = 0; k0 < K; k0 += 16) {
#pragma unroll
    for (int i = 0; i < 4; ++i) {
      int idx = tid + i * 256;
      int ar = idx >> 4, ak = idx & 15;
      As[ak][ar] = A[(size_t)(row0 + ar) * K + (k0 + ak)];
    }
#pragma unroll
    for (int i = 0; i < 4; ++i) {
      int idx = tid + i * 256;
      int br = idx >> 6, bc = idx & 63;
      Bs[br][bc] = Bm[(size_t)(k0 + br) * N + (col0 + bc)];
    }
    __syncthreads();
#pragma unroll
    for (int kk = 0; kk < 16; ++kk) {
      float4 a4 = *(const float4*)&As[kk][tm * 4];
      float4 b4 = *(const float4*)&Bs[kk][tn * 4];
      float av[4] = {a4.x, a4.y, a4.z, a4.w};
      float bv[4] = {b4.x, b4.y, b4.z, b4.w};
#pragma unroll
      for (int i = 0; i < 4; ++i)
#pragma unroll
        for (int j = 0; j < 4; ++j)
          acc[i][j] = fmaf(av[i], bv[j], acc[i][j]);
    }
    __syncthreads();
  }

  const int cbase = col0 + tn * 4;
  float4 bb = *(const float4*)&bias[cbase];
  float f0 = 1.f, f1 = 1.f;
  if (DO_ROPE) {
    int i0 = (cbase & 127) >> 1;  // pair index of (cbase, cbase+1)
    f0 = exp2f((float)i0 * -0.2076205059304601f);        // -log2(1e4)/64
    f1 = exp2f((float)(i0 + 1) * -0.2076205059304601f);
  }
#pragma unroll
  for (int i = 0; i < 4; ++i) {
    int row = row0 + tm * 4 + i;
    float v0 = acc[i][0] + bb.x, v1 = acc[i][1] + bb.y;
    float v2 = acc[i][2] + bb.z, v3 = acc[i][3] + bb.w;
    if (DO_ROPE) {
      int s = row & (S_ - 1);
      float p = (float)pos[s];
      float c0, s0, c1, s1;
      sincosf(p * f0, &s0, &c0);
      sincosf(p * f1, &s1, &c1);
      float r0 = v0 * c0 - v1 * s0;
      float r1 = v0 * s0 + v1 * c0;
      float r2 = v2 * c1 - v3 * s1;
      float r3 = v2 * s1 + v3 * c1;
      v0 = r0; v1 = r1; v2 = r2; v3 = r3;
    }
    uint2 pk;
    pk.x = (uint_t)f2bf(v0) | ((uint_t)f2bf(v1) << 16);
    pk.y = (uint_t)f2bf(v2) | ((uint_t)f2bf(v3) << 16);
    *(uint2*)&C[(size_t)row * N + cbase] = pk;
  }
}

// ---------------------------------------------------------------------------
// Causal MQA flash attention, bf16 MFMA (16x16x32).
// Block = 4 waves, QBLK=64 (16 q-rows/wave), KVBLK=64.
// QK^T computed swapped (S^T = K·Q^T) so each lane owns one q-row's scores:
//   lane holds q = lane&15, kv = kv0 + 16t + (lane>>4)*4 + r  (m89 C-layout).
// Softmax row-reduce = 2x shfl_xor(16,32). P -> per-wave LDS (bf16).
// PV computed as O^T = V^T · P^T (V stored transposed in LDS), so output
// frags give 4 contiguous d per lane -> float4 stores.
// ---------------------------------------------------------------------------
#define KPAD 136
#define VPAD 72
#define PPAD 72

__global__ __launch_bounds__(256) void attn_mfma_k(
    const ushort_t* __restrict__ Q, const ushort_t* __restrict__ K,
    const ushort_t* __restrict__ V, float* __restrict__ O) {
  __shared__ ushort_t Ksh[64][KPAD];   // [kv][feat] padded
  __shared__ ushort_t Vsh[128][VPAD];  // [feat][kv] transposed, padded
  __shared__ ushort_t Psh[4][16][PPAD];// per-wave [q][kv]

  const int qt = (gridDim.x - 1) - blockIdx.x;  // big tiles first
  const int h = blockIdx.y, b = blockIdx.z;
  const int tid = threadIdx.x;
  const int w = tid >> 6, lane = tid & 63;
  const int lr = lane & 15, lg = lane >> 4;
  const int q0 = qt * 64;
  const int qw = q0 + w * 16;       // wave min q row
  const int qg = qw + lr;           // this lane's q row
  const size_t bS = (size_t)b * S_;

  // Q fragments in registers: 4 k-groups of 32 features
  bf16x8 qf[4];
  {
    const ushort_t* qp = Q + (bS + qg) * DM_ + h * DK_ + lg * 8;
#pragma unroll
    for (int kg = 0; kg < 4; ++kg)
      qf[kg] = *(const bf16x8*)(qp + kg * 32);
  }

  f32x4 oacc[8];
#pragma unroll
  for (int i = 0; i < 8; ++i) oacc[i] = (f32x4){0.f, 0.f, 0.f, 0.f};
  float m = -INFINITY, l = 0.f;

  const int ntiles = qt + 1;
  for (int t0 = 0; t0 < ntiles; ++t0) {
    const int kv0 = t0 * 64;
    __syncthreads();
    // ---- stage K [64][128] -> Ksh (row-major, padded)
#pragma unroll
    for (int i = 0; i < 4; ++i) {
      int idx = tid + i * 256;
      int row = idx >> 4, c8 = idx & 15;
      bf16x8 kv8 = *(const bf16x8*)(K + (bS + kv0 + row) * DK_ + c8 * 8);
      *(bf16x8*)&Ksh[row][c8 * 8] = kv8;
    }
    // ---- stage V transposed -> Vsh[feat][kv]
#pragma unroll
    for (int i = 0; i < 4; ++i) {
      int row = tid & 63;
      int c8 = (tid >> 6) + 4 * i;
      bf16x8 vv = *(const bf16x8*)(V + (bS + kv0 + row) * DK_ + c8 * 8);
#pragma unroll
      for (int j = 0; j < 8; ++j)
        Vsh[c8 * 8 + j][row] = (ushort_t)vv[j];
    }
    __syncthreads();

    // ---- QK^T (swapped): st[t] = S^T sub-tile, kv = kv0+16t+lg*4+r, q = qg
    f32x4 st[4];
#pragma unroll
    for (int t = 0; t < 4; ++t) {
      f32x4 a = (f32x4){0.f, 0.f, 0.f, 0.f};
#pragma unroll
      for (int kg = 0; kg < 4; ++kg) {
        bf16x8 kf = *(const bf16x8*)&Ksh[t * 16 + lr][kg * 32 + lg * 8];
        a = __builtin_amdgcn_mfma_f32_16x16x32_bf16(kf, qf[kg], a, 0, 0, 0);
      }
      st[t] = a;
    }

    // ---- online softmax (per lane: one q-row, 16 kv values)
    const float scale = 0.08838834764831845f;  // 1/sqrt(128)
    const bool need_mask = (kv0 + 63) > qw;
    float sv[16];
    float tmax = -INFINITY;
#pragma unroll
    for (int t = 0; t < 4; ++t)
#pragma unroll
      for (int r = 0; r < 4; ++r) {
        float s = st[t][r] * scale;
        if (need_mask) {
          int kvi = kv0 + t * 16 + lg * 4 + r;
          if (kvi > qg) s = -INFINITY;
        }
        sv[t * 4 + r] = s;
        tmax = fmaxf(tmax, s);
      }
    tmax = fmaxf(tmax, __shfl_xor(tmax, 16));
    tmax = fmaxf(tmax, __shfl_xor(tmax, 32));
    const float mnew = fmaxf(m, tmax);
    const float corr = __expf(m - mnew);  // first tile: exp(-inf)=0
    float psum = 0.f;
    ushort_t ph[16];
#pragma unroll
    for (int i = 0; i < 16; ++i) {
      float p = __expf(sv[i] - mnew);
      psum += p;
      ph[i] = f2bf(p);
    }
    psum += __shfl_xor(psum, 16);
    psum += __shfl_xor(psum, 32);
    l = l * corr + psum;
    m = mnew;
#pragma unroll
    for (int i = 0; i < 8; ++i) {
      oacc[i][0] *= corr; oacc[i][1] *= corr;
      oacc[i][2] *= corr; oacc[i][3] *= corr;
    }
    // ---- P -> Psh (per-wave, no barrier needed)
#pragma unroll
    for (int t = 0; t < 4; ++t) {
      uint2 pk;
      pk.x = (uint_t)ph[t * 4 + 0] | ((uint_t)ph[t * 4 + 1] << 16);
      pk.y = (uint_t)ph[t * 4 + 2] | ((uint_t)ph[t * 4 + 3] << 16);
      *(uint2*)&Psh[w][lr][t * 16 + lg * 4] = pk;
    }

    // ---- PV: O^T += V^T · P^T
    bf16x8 pf0 = *(const bf16x8*)&Psh[w][lr][lg * 8];
    bf16x8 pf1 = *(const bf16x8*)&Psh[w][lr][32 + lg * 8];
#pragma unroll
    for (int dt = 0; dt < 8; ++dt) {
      bf16x8 vf0 = *(const bf16x8*)&Vsh[dt * 16 + lr][lg * 8];
      bf16x8 vf1 = *(const bf16x8*)&Vsh[dt * 16 + lr][32 + lg * 8];
      oacc[dt] = __builtin_amdgcn_mfma_f32_16x16x32_bf16(vf0, pf0, oacc[dt], 0, 0, 0);
      oacc[dt] = __builtin_amdgcn_mfma_f32_16x16x32_bf16(vf1, pf1, oacc[dt], 0, 0, 0);
    }
  }

  // ---- epilogue: O[q][d] = O^T / l ; lane holds q=lr, d = 16dt + 4lg + r
  const float invl = 1.0f / l;
  float* op = O + (bS + qg) * DM_ + h * DK_ + lg * 4;
#pragma unroll
  for (int dt = 0; dt < 8; ++dt) {
    float4 o;
    o.x = oacc[dt][0] * invl; o.y = oacc[dt][1] * invl;
    o.z = oacc[dt][2] * invl; o.w = oacc[dt][3] * invl;
    *(float4*)(op + dt * 16) = o;
  }
}

// ---------------------------------------------------------------------------
extern "C" void kernel_launch(void* const* d_in, const int* in_sizes, int n_in,
                              void* d_out, int out_size, void* d_ws,
                              size_t ws_size, hipStream_t stream) {
  const float* x  = (const float*)d_in[0];
  const int*   tp = (const int*)d_in[1];
  const float* Wq = (const float*)d_in[2];
  const float* bq = (const float*)d_in[3];
  const float* Wk = (const float*)d_in[4];
  const float* bk = (const float*)d_in[5];
  const float* Wv = (const float*)d_in[6];
  const float* bv = (const float*)d_in[7];
  const float* Wo = (const float*)d_in[8];
  const float* bo = (const float*)d_in[9];
  float* out = (float*)d_out;

  ushort_t* Qbf = (ushort_t*)d_ws;                 // M*DM bf16 = 16 MB
  ushort_t* Kbf = Qbf + (size_t)M_ * DM_;          // M*DK bf16 = 1 MB
  ushort_t* Vbf = Kbf + (size_t)M_ * DK_;          // M*DK bf16 = 1 MB
  float*    AT  = (float*)(Vbf + (size_t)M_ * DK_);// M*DM fp32 = 32 MB

  // Projections (bf16 out; RoPE fused for Q and K)
  gemm_bias_bf16_k<true><<<dim3(DM_ / 64, M_ / 64), 256, 0, stream>>>(
      x, Wq, bq, tp, Qbf, DM_, DM_);
  gemm_bias_bf16_k<true><<<dim3(DK_ / 64, M_ / 64), 256, 0, stream>>>(
      x, Wk, bk, tp, Kbf, DK_, DM_);
  gemm_bias_bf16_k<false><<<dim3(DK_ / 64, M_ / 64), 256, 0, stream>>>(
      x, Wv, bv, tp, Vbf, DK_, DM_);

  // Causal MQA attention (bf16 MFMA)
  attn_mfma_k<<<dim3(S_ / 64, H_, B_), 256, 0, stream>>>(Qbf, Kbf, Vbf, AT);

  // Output projection (fp32)
  gemm_bias_k<<<dim3(DM_ / 64, M_ / 64), 256, 0, stream>>>(AT, Wo, bo, out, DM_, DM_);
}

// Round 3
// 857.093 us; speedup vs baseline: 3.5502x; 1.6593x over previous
//
#include <hip/hip_runtime.h>
#include <math.h>

#define B_  2
#define S_  2048
#define DM_ 2048
#define H_  16
#define DK_ 128
#define M_  (B_ * S_)

typedef __attribute__((ext_vector_type(8))) short bf16x8;
typedef __attribute__((ext_vector_type(4))) float f32x4;
typedef unsigned short ushort_t;
typedef unsigned int uint_t;

__device__ inline ushort_t f2bf(float f) {
  union { float f; uint_t u; } v; v.f = f;
  uint_t u = v.u;
  uint_t r = (u + 0x7FFFu + ((u >> 16) & 1u)) >> 16;  // RNE
  return (ushort_t)r;
}

// ---------------------------------------------------------------------------
// fp32 -> bf16 elementwise convert (n multiple of 4)
// ---------------------------------------------------------------------------
__global__ void cvt_bf16_k(const float* __restrict__ in,
                           ushort_t* __restrict__ out, int n) {
  int i = (blockIdx.x * 256 + threadIdx.x) * 4;
  if (i >= n) return;
  float4 v = *(const float4*)(in + i);
  uint2 pk;
  pk.x = (uint_t)f2bf(v.x) | ((uint_t)f2bf(v.y) << 16);
  pk.y = (uint_t)f2bf(v.z) | ((uint_t)f2bf(v.w) << 16);
  *(uint2*)(out + i) = pk;
}

// ---------------------------------------------------------------------------
// fp32 [K][N] -> bf16 [N][K] tiled transpose-convert (64x64 tiles)
// ---------------------------------------------------------------------------
__global__ __launch_bounds__(256) void tconv_k(const float* __restrict__ W,
                                               ushort_t* __restrict__ WT,
                                               int K, int N) {
  __shared__ ushort_t Ls[64][72];
  const int k0 = blockIdx.y * 64, n0 = blockIdx.x * 64;
  const int t = threadIdx.x;
  const int r = t >> 4, c4 = t & 15;
#pragma unroll
  for (int i = 0; i < 4; ++i) {
    int row = r + i * 16;
    float4 v = *(const float4*)(W + (size_t)(k0 + row) * N + n0 + c4 * 4);
    Ls[row][c4 * 4 + 0] = f2bf(v.x);
    Ls[row][c4 * 4 + 1] = f2bf(v.y);
    Ls[row][c4 * 4 + 2] = f2bf(v.z);
    Ls[row][c4 * 4 + 3] = f2bf(v.w);
  }
  __syncthreads();
#pragma unroll
  for (int i = 0; i < 4; ++i) {
    int chunk = t + i * 256;               // 1024 chunks of 4 k-elems
    int nr = chunk >> 4, kc = chunk & 15;
    uint2 pk;
    pk.x = (uint_t)Ls[kc * 4 + 0][nr] | ((uint_t)Ls[kc * 4 + 1][nr] << 16);
    pk.y = (uint_t)Ls[kc * 4 + 2][nr] | ((uint_t)Ls[kc * 4 + 3][nr] << 16);
    *(uint2*)(WT + (size_t)(n0 + nr) * K + k0 + kc * 4) = pk;
  }
}

// ---------------------------------------------------------------------------
// bf16 MFMA GEMM: C[M x N] = A[M x K] @ Bt[N x K]^T + bias
// 128x128 tile, BK=32, 4 waves (2x2), 16x16x32 MFMA, global_load_lds(16B).
// EPI: 0 = fp32 out; 1 = RoPE + bf16 out; (bias always applied)
// ---------------------------------------------------------------------------
template <int EPI>
__global__ __launch_bounds__(256) void gemm_mfma_k(
    const ushort_t* __restrict__ A, const ushort_t* __restrict__ Bt,
    const float* __restrict__ bias, const int* __restrict__ pos,
    void* __restrict__ Cout, int N, int K) {
  __shared__ ushort_t Abuf[128 * 32];
  __shared__ ushort_t Bbuf[128 * 32];
  const int tid = threadIdx.x;
  const int lane = tid & 63;
  const int lr = lane & 15, lg = lane >> 4;
  const int w = tid >> 6, wm = w >> 1, wn = w & 1;
  const int row0 = blockIdx.y * 128, col0 = blockIdx.x * 128;

  f32x4 acc[4][4];
#pragma unroll
  for (int i = 0; i < 4; ++i)
#pragma unroll
    for (int j = 0; j < 4; ++j) acc[i][j] = (f32x4){0.f, 0.f, 0.f, 0.f};

  for (int k0 = 0; k0 < K; k0 += 32) {
    __syncthreads();
#pragma unroll
    for (int i = 0; i < 2; ++i) {
      int c = tid + i * 256;               // chunk 0..511: row=c>>2, kc=c&3
      int r = c >> 2, kc = c & 3;
      __builtin_amdgcn_global_load_lds(
          (const __attribute__((address_space(1))) void*)(
              A + (size_t)(row0 + r) * K + k0 + kc * 8),
          (__attribute__((address_space(3))) void*)(Abuf + c * 8), 16, 0, 0);
      __builtin_amdgcn_global_load_lds(
          (const __attribute__((address_space(1))) void*)(
              Bt + (size_t)(col0 + r) * K + k0 + kc * 8),
          (__attribute__((address_space(3))) void*)(Bbuf + c * 8), 16, 0, 0);
    }
    __syncthreads();

    bf16x8 af[4], bfr[4];
#pragma unroll
    for (int i = 0; i < 4; ++i) {
      af[i]  = *(const bf16x8*)&Abuf[(wm * 64 + i * 16 + lr) * 32 + lg * 8];
      bfr[i] = *(const bf16x8*)&Bbuf[(wn * 64 + i * 16 + lr) * 32 + lg * 8];
    }
#pragma unroll
    for (int mi = 0; mi < 4; ++mi)
#pragma unroll
      for (int ni = 0; ni < 4; ++ni)
        acc[mi][ni] = __builtin_amdgcn_mfma_f32_16x16x32_bf16(
            af[mi], bfr[ni], acc[mi][ni], 0, 0, 0);
  }

  // Epilogue. C layout (m89): col = lr, row = lg*4 + reg.
  const int colb = col0 + wn * 64;
#pragma unroll
  for (int mi = 0; mi < 4; ++mi) {
#pragma unroll
    for (int j = 0; j < 4; ++j) {
      const int row = row0 + wm * 64 + mi * 16 + lg * 4 + j;
      float pval = 0.f, sgn = 0.f;
      if (EPI == 1) pval = (float)pos[row & (S_ - 1)];
#pragma unroll
      for (int ni = 0; ni < 4; ++ni) {
        const int col = colb + ni * 16 + lr;
        float v = acc[mi][ni][j] + bias[col];
        if (EPI == 0) {
          ((float*)Cout)[(size_t)row * N + col] = v;
        } else {
          // RoPE: pair (2i,2i+1) across adjacent lanes
          float pv = __shfl_xor(v, 1);
          int pi = (col & 127) >> 1;
          float ang = pval * exp2f((float)pi * -0.2076205059304601f);
          float c, s;
          sincosf(ang, &s, &c);
          sgn = (lr & 1) ? s : -s;
          float rr = fmaf(pv, sgn, v * c);
          ((ushort_t*)Cout)[(size_t)row * N + col] = f2bf(rr);
        }
      }
    }
  }
}

// ---------------------------------------------------------------------------
// fp32 GEMM -> bf16 out, optional fused RoPE (used for K/V projections, N=128)
// ---------------------------------------------------------------------------
template <bool DO_ROPE>
__global__ __launch_bounds__(256) void gemm_bias_bf16_k(
    const float* __restrict__ A, const float* __restrict__ Bm,
    const float* __restrict__ bias, const int* __restrict__ pos,
    ushort_t* __restrict__ C, int N, int K) {
  __shared__ float As[16][68];
  __shared__ float Bs[16][68];
  const int tid = threadIdx.x;
  const int tn = tid & 15, tm = tid >> 4;
  const int row0 = blockIdx.y * 64, col0 = blockIdx.x * 64;
  float acc[4][4] = {};

  for (int k0 = 0; k0 < K; k0 += 16) {
#pragma unroll
    for (int i = 0; i < 4; ++i) {
      int idx = tid + i * 256;
      int ar = idx >> 4, ak = idx & 15;
      As[ak][ar] = A[(size_t)(row0 + ar) * K + (k0 + ak)];
    }
#pragma unroll
    for (int i = 0; i < 4; ++i) {
      int idx = tid + i * 256;
      int br = idx >> 6, bc = idx & 63;
      Bs[br][bc] = Bm[(size_t)(k0 + br) * N + (col0 + bc)];
    }
    __syncthreads();
#pragma unroll
    for (int kk = 0; kk < 16; ++kk) {
      float4 a4 = *(const float4*)&As[kk][tm * 4];
      float4 b4 = *(const float4*)&Bs[kk][tn * 4];
      float av[4] = {a4.x, a4.y, a4.z, a4.w};
      float bv[4] = {b4.x, b4.y, b4.z, b4.w};
#pragma unroll
      for (int i = 0; i < 4; ++i)
#pragma unroll
        for (int j = 0; j < 4; ++j)
          acc[i][j] = fmaf(av[i], bv[j], acc[i][j]);
    }
    __syncthreads();
  }

  const int cbase = col0 + tn * 4;
  float4 bb = *(const float4*)&bias[cbase];
  float f0 = 1.f, f1 = 1.f;
  if (DO_ROPE) {
    int i0 = (cbase & 127) >> 1;
    f0 = exp2f((float)i0 * -0.2076205059304601f);
    f1 = exp2f((float)(i0 + 1) * -0.2076205059304601f);
  }
#pragma unroll
  for (int i = 0; i < 4; ++i) {
    int row = row0 + tm * 4 + i;
    float v0 = acc[i][0] + bb.x, v1 = acc[i][1] + bb.y;
    float v2 = acc[i][2] + bb.z, v3 = acc[i][3] + bb.w;
    if (DO_ROPE) {
      int s = row & (S_ - 1);
      float p = (float)pos[s];
      float c0, s0, c1, s1;
      sincosf(p * f0, &s0, &c0);
      sincosf(p * f1, &s1, &c1);
      float r0 = v0 * c0 - v1 * s0;
      float r1 = v0 * s0 + v1 * c0;
      float r2 = v2 * c1 - v3 * s1;
      float r3 = v2 * s1 + v3 * c1;
      v0 = r0; v1 = r1; v2 = r2; v3 = r3;
    }
    uint2 pk;
    pk.x = (uint_t)f2bf(v0) | ((uint_t)f2bf(v1) << 16);
    pk.y = (uint_t)f2bf(v2) | ((uint_t)f2bf(v3) << 16);
    *(uint2*)&C[(size_t)row * N + cbase] = pk;
  }
}

// ---------------------------------------------------------------------------
// Causal MQA flash attention, bf16 MFMA (16x16x32). bf16 output.
// ---------------------------------------------------------------------------
#define KPAD 136
#define VPAD 72
#define PPAD 72

__global__ __launch_bounds__(256) void attn_mfma_k(
    const ushort_t* __restrict__ Q, const ushort_t* __restrict__ K,
    const ushort_t* __restrict__ V, ushort_t* __restrict__ O) {
  __shared__ ushort_t Ksh[64][KPAD];
  __shared__ ushort_t Vsh[128][VPAD];
  __shared__ ushort_t Psh[4][16][PPAD];

  const int qt = (gridDim.x - 1) - blockIdx.x;
  const int h = blockIdx.y, b = blockIdx.z;
  const int tid = threadIdx.x;
  const int w = tid >> 6, lane = tid & 63;
  const int lr = lane & 15, lg = lane >> 4;
  const int qw = qt * 64 + w * 16;
  const int qg = qw + lr;
  const size_t bS = (size_t)b * S_;

  bf16x8 qf[4];
  {
    const ushort_t* qp = Q + (bS + qg) * DM_ + h * DK_ + lg * 8;
#pragma unroll
    for (int kg = 0; kg < 4; ++kg) qf[kg] = *(const bf16x8*)(qp + kg * 32);
  }

  f32x4 oacc[8];
#pragma unroll
  for (int i = 0; i < 8; ++i) oacc[i] = (f32x4){0.f, 0.f, 0.f, 0.f};
  float m = -INFINITY, l = 0.f;

  const int ntiles = qt + 1;
  for (int t0 = 0; t0 < ntiles; ++t0) {
    const int kv0 = t0 * 64;
    __syncthreads();
#pragma unroll
    for (int i = 0; i < 4; ++i) {
      int idx = tid + i * 256;
      int row = idx >> 4, c8 = idx & 15;
      bf16x8 kv8 = *(const bf16x8*)(K + (bS + kv0 + row) * DK_ + c8 * 8);
      *(bf16x8*)&Ksh[row][c8 * 8] = kv8;
    }
#pragma unroll
    for (int i = 0; i < 4; ++i) {
      int row = tid & 63;
      int c8 = (tid >> 6) + 4 * i;
      bf16x8 vv = *(const bf16x8*)(V + (bS + kv0 + row) * DK_ + c8 * 8);
#pragma unroll
      for (int j = 0; j < 8; ++j) Vsh[c8 * 8 + j][row] = (ushort_t)vv[j];
    }
    __syncthreads();

    f32x4 st[4];
#pragma unroll
    for (int t = 0; t < 4; ++t) {
      f32x4 a = (f32x4){0.f, 0.f, 0.f, 0.f};
#pragma unroll
      for (int kg = 0; kg < 4; ++kg) {
        bf16x8 kf = *(const bf16x8*)&Ksh[t * 16 + lr][kg * 32 + lg * 8];
        a = __builtin_amdgcn_mfma_f32_16x16x32_bf16(kf, qf[kg], a, 0, 0, 0);
      }
      st[t] = a;
    }

    const float scale = 0.08838834764831845f;
    const bool need_mask = (kv0 + 63) > qw;
    float sv[16];
    float tmax = -INFINITY;
#pragma unroll
    for (int t = 0; t < 4; ++t)
#pragma unroll
      for (int r = 0; r < 4; ++r) {
        float s = st[t][r] * scale;
        if (need_mask) {
          int kvi = kv0 + t * 16 + lg * 4 + r;
          if (kvi > qg) s = -INFINITY;
        }
        sv[t * 4 + r] = s;
        tmax = fmaxf(tmax, s);
      }
    tmax = fmaxf(tmax, __shfl_xor(tmax, 16));
    tmax = fmaxf(tmax, __shfl_xor(tmax, 32));
    const float mnew = fmaxf(m, tmax);
    const float corr = __expf(m - mnew);
    float psum = 0.f;
    ushort_t ph[16];
#pragma unroll
    for (int i = 0; i < 16; ++i) {
      float p = __expf(sv[i] - mnew);
      psum += p;
      ph[i] = f2bf(p);
    }
    psum += __shfl_xor(psum, 16);
    psum += __shfl_xor(psum, 32);
    l = l * corr + psum;
    m = mnew;
#pragma unroll
    for (int i = 0; i < 8; ++i) {
      oacc[i][0] *= corr; oacc[i][1] *= corr;
      oacc[i][2] *= corr; oacc[i][3] *= corr;
    }
#pragma unroll
    for (int t = 0; t < 4; ++t) {
      uint2 pk;
      pk.x = (uint_t)ph[t * 4 + 0] | ((uint_t)ph[t * 4 + 1] << 16);
      pk.y = (uint_t)ph[t * 4 + 2] | ((uint_t)ph[t * 4 + 3] << 16);
      *(uint2*)&Psh[w][lr][t * 16 + lg * 4] = pk;
    }

    bf16x8 pf0 = *(const bf16x8*)&Psh[w][lr][lg * 8];
    bf16x8 pf1 = *(const bf16x8*)&Psh[w][lr][32 + lg * 8];
#pragma unroll
    for (int dt = 0; dt < 8; ++dt) {
      bf16x8 vf0 = *(const bf16x8*)&Vsh[dt * 16 + lr][lg * 8];
      bf16x8 vf1 = *(const bf16x8*)&Vsh[dt * 16 + lr][32 + lg * 8];
      oacc[dt] = __builtin_amdgcn_mfma_f32_16x16x32_bf16(vf0, pf0, oacc[dt], 0, 0, 0);
      oacc[dt] = __builtin_amdgcn_mfma_f32_16x16x32_bf16(vf1, pf1, oacc[dt], 0, 0, 0);
    }
  }

  const float invl = 1.0f / l;
  ushort_t* op = O + (bS + qg) * DM_ + h * DK_ + lg * 4;
#pragma unroll
  for (int dt = 0; dt < 8; ++dt) {
    uint2 pk;
    pk.x = (uint_t)f2bf(oacc[dt][0] * invl) |
           ((uint_t)f2bf(oacc[dt][1] * invl) << 16);
    pk.y = (uint_t)f2bf(oacc[dt][2] * invl) |
           ((uint_t)f2bf(oacc[dt][3] * invl) << 16);
    *(uint2*)(op + dt * 16) = pk;
  }
}

// ---------------------------------------------------------------------------
extern "C" void kernel_launch(void* const* d_in, const int* in_sizes, int n_in,
                              void* d_out, int out_size, void* d_ws,
                              size_t ws_size, hipStream_t stream) {
  const float* x  = (const float*)d_in[0];
  const int*   tp = (const int*)d_in[1];
  const float* Wq = (const float*)d_in[2];
  const float* bq = (const float*)d_in[3];
  const float* Wk = (const float*)d_in[4];
  const float* bk = (const float*)d_in[5];
  const float* Wv = (const float*)d_in[6];
  const float* bv = (const float*)d_in[7];
  const float* Wo = (const float*)d_in[8];
  const float* bo = (const float*)d_in[9];
  float* out = (float*)d_out;

  ushort_t* Xbf = (ushort_t*)d_ws;                   // M*DM   bf16 = 16 MB
  ushort_t* WqT = Xbf + (size_t)M_ * DM_;            // DM*DM  bf16 =  8 MB
  ushort_t* WoT = WqT + (size_t)DM_ * DM_;           // DM*DM  bf16 =  8 MB
  ushort_t* Qbf = WoT + (size_t)DM_ * DM_;           // M*DM   bf16 = 16 MB
  ushort_t* Kbf = Qbf + (size_t)M_ * DM_;            // M*DK   bf16 =  1 MB
  ushort_t* Vbf = Kbf + (size_t)M_ * DK_;            // M*DK   bf16 =  1 MB
  ushort_t* ATb = Vbf + (size_t)M_ * DK_;            // M*DM   bf16 = 16 MB

  // Converts
  cvt_bf16_k<<<(M_ * DM_ / 4 + 255) / 256, 256, 0, stream>>>(x, Xbf, M_ * DM_);
  tconv_k<<<dim3(DM_ / 64, DM_ / 64), 256, 0, stream>>>(Wq, WqT, DM_, DM_);
  tconv_k<<<dim3(DM_ / 64, DM_ / 64), 256, 0, stream>>>(Wo, WoT, DM_, DM_);

  // K/V projections (fp32 path, fused RoPE for K)
  gemm_bias_bf16_k<true><<<dim3(DK_ / 64, M_ / 64), 256, 0, stream>>>(
      x, Wk, bk, tp, Kbf, DK_, DM_);
  gemm_bias_bf16_k<false><<<dim3(DK_ / 64, M_ / 64), 256, 0, stream>>>(
      x, Wv, bv, tp, Vbf, DK_, DM_);

  // Q projection (bf16 MFMA, fused bias+RoPE, bf16 out)
  gemm_mfma_k<1><<<dim3(DM_ / 128, M_ / 128), 256, 0, stream>>>(
      Xbf, WqT, bq, tp, (void*)Qbf, DM_, DM_);

  // Causal MQA attention (bf16 MFMA, bf16 out)
  attn_mfma_k<<<dim3(S_ / 64, H_, B_), 256, 0, stream>>>(Qbf, Kbf, Vbf, ATb);

  // Output projection (bf16 MFMA, fp32 out)
  gemm_mfma_k<0><<<dim3(DM_ / 128, M_ / 128), 256, 0, stream>>>(
      ATb, WoT, bo, tp, (void*)out, DM_, DM_);
}

// Round 4
// 399.602 us; speedup vs baseline: 7.6146x; 2.1449x over previous
//
#include <hip/hip_runtime.h>
#include <math.h>

#define B_  2
#define S_  2048
#define DM_ 2048
#define H_  16
#define DK_ 128
#define M_  (B_ * S_)

typedef __attribute__((ext_vector_type(8))) short bf16x8;
typedef __attribute__((ext_vector_type(4))) float f32x4;
typedef unsigned short ushort_t;
typedef unsigned int uint_t;

__device__ inline ushort_t f2bf(float f) {
  union { float f; uint_t u; } v; v.f = f;
  uint_t u = v.u;
  uint_t r = (u + 0x7FFFu + ((u >> 16) & 1u)) >> 16;  // RNE
  return (ushort_t)r;
}

// ---------------------------------------------------------------------------
// fp32 -> bf16 elementwise convert
// ---------------------------------------------------------------------------
__global__ void cvt_bf16_k(const float* __restrict__ in,
                           ushort_t* __restrict__ out, int n) {
  int i = (blockIdx.x * 256 + threadIdx.x) * 4;
  if (i >= n) return;
  float4 v = *(const float4*)(in + i);
  uint2 pk;
  pk.x = (uint_t)f2bf(v.x) | ((uint_t)f2bf(v.y) << 16);
  pk.y = (uint_t)f2bf(v.z) | ((uint_t)f2bf(v.w) << 16);
  *(uint2*)(out + i) = pk;
}

// ---------------------------------------------------------------------------
// RoPE table: tab[s*64 + i] = (cos, sin) of pos[s] * 10000^(-i/64)
// ---------------------------------------------------------------------------
__global__ void rope_tab_k(const int* __restrict__ pos,
                           float2* __restrict__ tab) {
  int idx = blockIdx.x * 256 + threadIdx.x;  // S_*64 total
  int s = idx >> 6, i = idx & 63;
  float ang = (float)pos[s] * exp2f((float)i * -0.2076205059304601f);
  float sn, cs;
  sincosf(ang, &sn, &cs);
  tab[idx] = make_float2(cs, sn);
}

// ---------------------------------------------------------------------------
// fp32 [K][N] -> bf16 [N][K] tiled transpose-convert (64x64 tiles)
// ---------------------------------------------------------------------------
__global__ __launch_bounds__(256) void tconv_k(const float* __restrict__ W,
                                               ushort_t* __restrict__ WT,
                                               int K, int N) {
  __shared__ ushort_t Ls[64][72];
  const int k0 = blockIdx.y * 64, n0 = blockIdx.x * 64;
  const int t = threadIdx.x;
  const int r = t >> 4, c4 = t & 15;
#pragma unroll
  for (int i = 0; i < 4; ++i) {
    int row = r + i * 16;
    float4 v = *(const float4*)(W + (size_t)(k0 + row) * N + n0 + c4 * 4);
    Ls[row][c4 * 4 + 0] = f2bf(v.x);
    Ls[row][c4 * 4 + 1] = f2bf(v.y);
    Ls[row][c4 * 4 + 2] = f2bf(v.z);
    Ls[row][c4 * 4 + 3] = f2bf(v.w);
  }
  __syncthreads();
#pragma unroll
  for (int i = 0; i < 4; ++i) {
    int chunk = t + i * 256;
    int nr = chunk >> 4, kc = chunk & 15;
    uint2 pk;
    pk.x = (uint_t)Ls[kc * 4 + 0][nr] | ((uint_t)Ls[kc * 4 + 1][nr] << 16);
    pk.y = (uint_t)Ls[kc * 4 + 2][nr] | ((uint_t)Ls[kc * 4 + 3][nr] << 16);
    *(uint2*)(WT + (size_t)(n0 + nr) * K + k0 + kc * 4) = pk;
  }
}

// ---------------------------------------------------------------------------
// bf16 MFMA GEMM: C = A[M x K] @ Bt[N x K]^T + bias, LDS-staged epilogue.
// 128x128 tile, BK=32, 4 waves (2x2), 16x16x32 MFMA, global_load_lds(16B).
// EPI: 0 = fp32 out (C1, stride N)
//      1 = RoPE + bf16 out (C1, stride N)
//      2 = KV fused: cols<128 -> RoPE+bf16 to C1 (stride 128, bias),
//                    cols>=128 -> bf16 to C2 (stride 128, bias2)
// ---------------------------------------------------------------------------
template <int EPI>
__global__ __launch_bounds__(256) void gemm_mfma_k(
    const ushort_t* __restrict__ A, const ushort_t* __restrict__ Bt,
    const float* __restrict__ bias, const float* __restrict__ bias2,
    const float2* __restrict__ tab,
    void* __restrict__ C1, void* __restrict__ C2, int N, int K) {
  __shared__ ushort_t Abuf[128 * 32];
  __shared__ ushort_t Bbuf[128 * 32];
  __shared__ float Ep[32][132];

  // bijective XCD swizzle (nwg % 8 == 0 for all our grids)
  const int nwg = gridDim.x * gridDim.y;
  const int orig = blockIdx.y * gridDim.x + blockIdx.x;
  const int qq = nwg >> 3;
  const int swz = (orig & 7) * qq + (orig >> 3);
  const int bx = swz % gridDim.x, by = swz / gridDim.x;

  const int tid = threadIdx.x;
  const int lane = tid & 63;
  const int lr = lane & 15, lg = lane >> 4;
  const int w = tid >> 6, wm = w >> 1, wn = w & 1;
  const int row0 = by * 128, col0 = bx * 128;

  f32x4 acc[4][4];
#pragma unroll
  for (int i = 0; i < 4; ++i)
#pragma unroll
    for (int j = 0; j < 4; ++j) acc[i][j] = (f32x4){0.f, 0.f, 0.f, 0.f};

  for (int k0 = 0; k0 < K; k0 += 32) {
    __syncthreads();
#pragma unroll
    for (int i = 0; i < 2; ++i) {
      int c = tid + i * 256;
      int r = c >> 2, kc = c & 3;
      __builtin_amdgcn_global_load_lds(
          (const __attribute__((address_space(1))) void*)(
              A + (size_t)(row0 + r) * K + k0 + kc * 8),
          (__attribute__((address_space(3))) void*)(Abuf + c * 8), 16, 0, 0);
      __builtin_amdgcn_global_load_lds(
          (const __attribute__((address_space(1))) void*)(
              Bt + (size_t)(col0 + r) * K + k0 + kc * 8),
          (__attribute__((address_space(3))) void*)(Bbuf + c * 8), 16, 0, 0);
    }
    __syncthreads();

    bf16x8 af[4], bfr[4];
#pragma unroll
    for (int i = 0; i < 4; ++i) {
      af[i]  = *(const bf16x8*)&Abuf[(wm * 64 + i * 16 + lr) * 32 + lg * 8];
      bfr[i] = *(const bf16x8*)&Bbuf[(wn * 64 + i * 16 + lr) * 32 + lg * 8];
    }
#pragma unroll
    for (int mi = 0; mi < 4; ++mi)
#pragma unroll
      for (int ni = 0; ni < 4; ++ni)
        acc[mi][ni] = __builtin_amdgcn_mfma_f32_16x16x32_bf16(
            af[mi], bfr[ni], acc[mi][ni], 0, 0, 0);
  }

  // ---- LDS-staged epilogue: 4 rounds of [32 rows x 128 cols] fp32
  const int r5 = tid >> 3;            // 0..31 staged row
  const int c0 = (tid & 7) * 16;      // 0..112 col base (16 cols/thread)
  const int lrow = (r5 >> 4) * 64 + (r5 & 15);
  const int gcol = col0 + c0;

#pragma unroll
  for (int mi = 0; mi < 4; ++mi) {
    __syncthreads();
#pragma unroll
    for (int ni = 0; ni < 4; ++ni)
#pragma unroll
      for (int j = 0; j < 4; ++j)
        Ep[wm * 16 + lg * 4 + j][wn * 64 + ni * 16 + lr] = acc[mi][ni][j];
    __syncthreads();

    const int grow = row0 + lrow + mi * 16;
    float v[16];
#pragma unroll
    for (int q4 = 0; q4 < 4; ++q4) {
      float4 f = *(const float4*)&Ep[r5][c0 + q4 * 4];
      v[q4 * 4 + 0] = f.x; v[q4 * 4 + 1] = f.y;
      v[q4 * 4 + 2] = f.z; v[q4 * 4 + 3] = f.w;
    }

    if (EPI == 0) {
      float* Cp = (float*)C1 + (size_t)grow * N + gcol;
#pragma unroll
      for (int q4 = 0; q4 < 4; ++q4) {
        float4 bb = *(const float4*)&bias[gcol + q4 * 4];
        float4 o;
        o.x = v[q4 * 4 + 0] + bb.x; o.y = v[q4 * 4 + 1] + bb.y;
        o.z = v[q4 * 4 + 2] + bb.z; o.w = v[q4 * 4 + 3] + bb.w;
        *(float4*)(Cp + q4 * 4) = o;
      }
    } else if (EPI == 1) {
      const float2* tp = tab + (size_t)(grow & (S_ - 1)) * 64 + ((gcol & 127) >> 1);
      ushort_t hs[16];
#pragma unroll
      for (int p = 0; p < 8; ++p) {
        float2 cs = tp[p];
        float v0 = v[2 * p]     + bias[gcol + 2 * p];
        float v1 = v[2 * p + 1] + bias[gcol + 2 * p + 1];
        hs[2 * p]     = f2bf(v0 * cs.x - v1 * cs.y);
        hs[2 * p + 1] = f2bf(v0 * cs.y + v1 * cs.x);
      }
      uint4 u0, u1;
      u0.x = (uint_t)hs[0] | ((uint_t)hs[1] << 16);
      u0.y = (uint_t)hs[2] | ((uint_t)hs[3] << 16);
      u0.z = (uint_t)hs[4] | ((uint_t)hs[5] << 16);
      u0.w = (uint_t)hs[6] | ((uint_t)hs[7] << 16);
      u1.x = (uint_t)hs[8] | ((uint_t)hs[9] << 16);
      u1.y = (uint_t)hs[10] | ((uint_t)hs[11] << 16);
      u1.z = (uint_t)hs[12] | ((uint_t)hs[13] << 16);
      u1.w = (uint_t)hs[14] | ((uint_t)hs[15] << 16);
      ushort_t* Cp = (ushort_t*)C1 + (size_t)grow * N + gcol;
      ((uint4*)Cp)[0] = u0;
      ((uint4*)Cp)[1] = u1;
    } else {  // EPI == 2: fused K|V
      ushort_t hs[16];
      if (gcol < 128) {  // K side: RoPE
        const float2* tp = tab + (size_t)(grow & (S_ - 1)) * 64 + (gcol >> 1);
#pragma unroll
        for (int p = 0; p < 8; ++p) {
          float2 cs = tp[p];
          float v0 = v[2 * p]     + bias[gcol + 2 * p];
          float v1 = v[2 * p + 1] + bias[gcol + 2 * p + 1];
          hs[2 * p]     = f2bf(v0 * cs.x - v1 * cs.y);
          hs[2 * p + 1] = f2bf(v0 * cs.y + v1 * cs.x);
        }
      } else {  // V side: plain bias
#pragma unroll
        for (int k = 0; k < 16; ++k)
          hs[k] = f2bf(v[k] + bias2[gcol - 128 + k]);
      }
      uint4 u0, u1;
      u0.x = (uint_t)hs[0] | ((uint_t)hs[1] << 16);
      u0.y = (uint_t)hs[2] | ((uint_t)hs[3] << 16);
      u0.z = (uint_t)hs[4] | ((uint_t)hs[5] << 16);
      u0.w = (uint_t)hs[6] | ((uint_t)hs[7] << 16);
      u1.x = (uint_t)hs[8] | ((uint_t)hs[9] << 16);
      u1.y = (uint_t)hs[10] | ((uint_t)hs[11] << 16);
      u1.z = (uint_t)hs[12] | ((uint_t)hs[13] << 16);
      u1.w = (uint_t)hs[14] | ((uint_t)hs[15] << 16);
      ushort_t* Cp = (gcol < 128)
          ? (ushort_t*)C1 + (size_t)grow * DK_ + gcol
          : (ushort_t*)C2 + (size_t)grow * DK_ + (gcol - 128);
      ((uint4*)Cp)[0] = u0;
      ((uint4*)Cp)[1] = u1;
    }
  }
}

// ---------------------------------------------------------------------------
// Causal MQA flash attention, bf16 MFMA (16x16x32). bf16 output.
// ---------------------------------------------------------------------------
#define KPAD 136
#define VPAD 72
#define PPAD 72

__global__ __launch_bounds__(256) void attn_mfma_k(
    const ushort_t* __restrict__ Q, const ushort_t* __restrict__ K,
    const ushort_t* __restrict__ V, ushort_t* __restrict__ O) {
  __shared__ ushort_t Ksh[64][KPAD];
  __shared__ ushort_t Vsh[128][VPAD];
  __shared__ ushort_t Psh[4][16][PPAD];

  const int qt = (gridDim.x - 1) - blockIdx.x;
  const int h = blockIdx.y, b = blockIdx.z;
  const int tid = threadIdx.x;
  const int w = tid >> 6, lane = tid & 63;
  const int lr = lane & 15, lg = lane >> 4;
  const int qw = qt * 64 + w * 16;
  const int qg = qw + lr;
  const size_t bS = (size_t)b * S_;

  bf16x8 qf[4];
  {
    const ushort_t* qp = Q + (bS + qg) * DM_ + h * DK_ + lg * 8;
#pragma unroll
    for (int kg = 0; kg < 4; ++kg) qf[kg] = *(const bf16x8*)(qp + kg * 32);
  }

  f32x4 oacc[8];
#pragma unroll
  for (int i = 0; i < 8; ++i) oacc[i] = (f32x4){0.f, 0.f, 0.f, 0.f};
  float m = -INFINITY, l = 0.f;

  const int ntiles = qt + 1;
  for (int t0 = 0; t0 < ntiles; ++t0) {
    const int kv0 = t0 * 64;
    __syncthreads();
#pragma unroll
    for (int i = 0; i < 4; ++i) {
      int idx = tid + i * 256;
      int row = idx >> 4, c8 = idx & 15;
      bf16x8 kv8 = *(const bf16x8*)(K + (bS + kv0 + row) * DK_ + c8 * 8);
      *(bf16x8*)&Ksh[row][c8 * 8] = kv8;
    }
#pragma unroll
    for (int i = 0; i < 4; ++i) {
      int row = tid & 63;
      int c8 = (tid >> 6) + 4 * i;
      bf16x8 vv = *(const bf16x8*)(V + (bS + kv0 + row) * DK_ + c8 * 8);
#pragma unroll
      for (int j = 0; j < 8; ++j) Vsh[c8 * 8 + j][row] = (ushort_t)vv[j];
    }
    __syncthreads();

    f32x4 st[4];
#pragma unroll
    for (int t = 0; t < 4; ++t) {
      f32x4 a = (f32x4){0.f, 0.f, 0.f, 0.f};
#pragma unroll
      for (int kg = 0; kg < 4; ++kg) {
        bf16x8 kf = *(const bf16x8*)&Ksh[t * 16 + lr][kg * 32 + lg * 8];
        a = __builtin_amdgcn_mfma_f32_16x16x32_bf16(kf, qf[kg], a, 0, 0, 0);
      }
      st[t] = a;
    }

    const float scale = 0.08838834764831845f;
    const bool need_mask = (kv0 + 63) > qw;
    float sv[16];
    float tmax = -INFINITY;
#pragma unroll
    for (int t = 0; t < 4; ++t)
#pragma unroll
      for (int r = 0; r < 4; ++r) {
        float s = st[t][r] * scale;
        if (need_mask) {
          int kvi = kv0 + t * 16 + lg * 4 + r;
          if (kvi > qg) s = -INFINITY;
        }
        sv[t * 4 + r] = s;
        tmax = fmaxf(tmax, s);
      }
    tmax = fmaxf(tmax, __shfl_xor(tmax, 16));
    tmax = fmaxf(tmax, __shfl_xor(tmax, 32));
    const float mnew = fmaxf(m, tmax);
    const float corr = __expf(m - mnew);
    float psum = 0.f;
    ushort_t ph[16];
#pragma unroll
    for (int i = 0; i < 16; ++i) {
      float p = __expf(sv[i] - mnew);
      psum += p;
      ph[i] = f2bf(p);
    }
    psum += __shfl_xor(psum, 16);
    psum += __shfl_xor(psum, 32);
    l = l * corr + psum;
    m = mnew;
#pragma unroll
    for (int i = 0; i < 8; ++i) {
      oacc[i][0] *= corr; oacc[i][1] *= corr;
      oacc[i][2] *= corr; oacc[i][3] *= corr;
    }
#pragma unroll
    for (int t = 0; t < 4; ++t) {
      uint2 pk;
      pk.x = (uint_t)ph[t * 4 + 0] | ((uint_t)ph[t * 4 + 1] << 16);
      pk.y = (uint_t)ph[t * 4 + 2] | ((uint_t)ph[t * 4 + 3] << 16);
      *(uint2*)&Psh[w][lr][t * 16 + lg * 4] = pk;
    }

    bf16x8 pf0 = *(const bf16x8*)&Psh[w][lr][lg * 8];
    bf16x8 pf1 = *(const bf16x8*)&Psh[w][lr][32 + lg * 8];
#pragma unroll
    for (int dt = 0; dt < 8; ++dt) {
      bf16x8 vf0 = *(const bf16x8*)&Vsh[dt * 16 + lr][lg * 8];
      bf16x8 vf1 = *(const bf16x8*)&Vsh[dt * 16 + lr][32 + lg * 8];
      oacc[dt] = __builtin_amdgcn_mfma_f32_16x16x32_bf16(vf0, pf0, oacc[dt], 0, 0, 0);
      oacc[dt] = __builtin_amdgcn_mfma_f32_16x16x32_bf16(vf1, pf1, oacc[dt], 0, 0, 0);
    }
  }

  const float invl = 1.0f / l;
  ushort_t* op = O + (bS + qg) * DM_ + h * DK_ + lg * 4;
#pragma unroll
  for (int dt = 0; dt < 8; ++dt) {
    uint2 pk;
    pk.x = (uint_t)f2bf(oacc[dt][0] * invl) |
           ((uint_t)f2bf(oacc[dt][1] * invl) << 16);
    pk.y = (uint_t)f2bf(oacc[dt][2] * invl) |
           ((uint_t)f2bf(oacc[dt][3] * invl) << 16);
    *(uint2*)(op + dt * 16) = pk;
  }
}

// ---------------------------------------------------------------------------
extern "C" void kernel_launch(void* const* d_in, const int* in_sizes, int n_in,
                              void* d_out, int out_size, void* d_ws,
                              size_t ws_size, hipStream_t stream) {
  const float* x  = (const float*)d_in[0];
  const int*   tp = (const int*)d_in[1];
  const float* Wq = (const float*)d_in[2];
  const float* bq = (const float*)d_in[3];
  const float* Wk = (const float*)d_in[4];
  const float* bk = (const float*)d_in[5];
  const float* Wv = (const float*)d_in[6];
  const float* bv = (const float*)d_in[7];
  const float* Wo = (const float*)d_in[8];
  const float* bo = (const float*)d_in[9];
  float* out = (float*)d_out;

  ushort_t* Xbf  = (ushort_t*)d_ws;                   // M*DM    16 MB
  ushort_t* WqT  = Xbf + (size_t)M_ * DM_;            // DM*DM    8 MB
  ushort_t* WoT  = WqT + (size_t)DM_ * DM_;           // DM*DM    8 MB
  ushort_t* WkvT = WoT + (size_t)DM_ * DM_;           // 256*DM   1 MB
  ushort_t* Qbf  = WkvT + (size_t)256 * DM_;          // M*DM    16 MB
  ushort_t* Kbf  = Qbf + (size_t)M_ * DM_;            // M*DK     1 MB
  ushort_t* Vbf  = Kbf + (size_t)M_ * DK_;            // M*DK     1 MB
  ushort_t* ATb  = Vbf + (size_t)M_ * DK_;            // M*DM    16 MB
  float2*   tab  = (float2*)(ATb + (size_t)M_ * DM_); // S*64     1 MB

  // Converts + RoPE table
  cvt_bf16_k<<<(M_ * DM_ / 4 + 255) / 256, 256, 0, stream>>>(x, Xbf, M_ * DM_);
  tconv_k<<<dim3(DM_ / 64, DM_ / 64), 256, 0, stream>>>(Wq, WqT, DM_, DM_);
  tconv_k<<<dim3(DM_ / 64, DM_ / 64), 256, 0, stream>>>(Wo, WoT, DM_, DM_);
  tconv_k<<<dim3(DK_ / 64, DM_ / 64), 256, 0, stream>>>(Wk, WkvT, DM_, DK_);
  tconv_k<<<dim3(DK_ / 64, DM_ / 64), 256, 0, stream>>>(
      Wv, WkvT + (size_t)DK_ * DM_, DM_, DK_);
  rope_tab_k<<<S_ * 64 / 256, 256, 0, stream>>>(tp, tab);

  // Q projection (MFMA, fused bias+RoPE, bf16 out)
  gemm_mfma_k<1><<<dim3(DM_ / 128, M_ / 128), 256, 0, stream>>>(
      Xbf, WqT, bq, nullptr, tab, (void*)Qbf, nullptr, DM_, DM_);

  // K|V fused projection (MFMA, K gets RoPE)
  gemm_mfma_k<2><<<dim3(2, M_ / 128), 256, 0, stream>>>(
      Xbf, WkvT, bk, bv, tab, (void*)Kbf, (void*)Vbf, DK_, DM_);

  // Causal MQA attention (bf16 MFMA, bf16 out)
  attn_mfma_k<<<dim3(S_ / 64, H_, B_), 256, 0, stream>>>(Qbf, Kbf, Vbf, ATb);

  // Output projection (MFMA, fp32 out)
  gemm_mfma_k<0><<<dim3(DM_ / 128, M_ / 128), 256, 0, stream>>>(
      ATb, WoT, bo, nullptr, nullptr, (void*)out, nullptr, DM_, DM_);
}

// Round 5
// 282.679 us; speedup vs baseline: 10.7642x; 1.4136x over previous
//
#include <hip/hip_runtime.h>
#include <math.h>

#define B_  2
#define S_  2048
#define DM_ 2048
#define H_  16
#define DK_ 128
#define M_  (B_ * S_)

typedef __attribute__((ext_vector_type(8))) short bf16x8;
typedef __attribute__((ext_vector_type(4))) float f32x4;
typedef unsigned short ushort_t;
typedef unsigned int uint_t;

__device__ inline ushort_t f2bf(float f) {
  union { float f; uint_t u; } v; v.f = f;
  uint_t u = v.u;
  uint_t r = (u + 0x7FFFu + ((u >> 16) & 1u)) >> 16;  // RNE
  return (ushort_t)r;
}

// ---------------------------------------------------------------------------
// fp32 -> bf16 elementwise convert
// ---------------------------------------------------------------------------
__global__ void cvt_bf16_k(const float* __restrict__ in,
                           ushort_t* __restrict__ out, int n) {
  int i = (blockIdx.x * 256 + threadIdx.x) * 4;
  if (i >= n) return;
  float4 v = *(const float4*)(in + i);
  uint2 pk;
  pk.x = (uint_t)f2bf(v.x) | ((uint_t)f2bf(v.y) << 16);
  pk.y = (uint_t)f2bf(v.z) | ((uint_t)f2bf(v.w) << 16);
  *(uint2*)(out + i) = pk;
}

// ---------------------------------------------------------------------------
// RoPE table: tab[s*64 + i] = (cos, sin) of pos[s] * 10000^(-i/64)
// ---------------------------------------------------------------------------
__global__ void rope_tab_k(const int* __restrict__ pos,
                           float2* __restrict__ tab) {
  int idx = blockIdx.x * 256 + threadIdx.x;
  int s = idx >> 6, i = idx & 63;
  float ang = (float)pos[s] * exp2f((float)i * -0.2076205059304601f);
  float sn, cs;
  sincosf(ang, &sn, &cs);
  tab[idx] = make_float2(cs, sn);
}

// ---------------------------------------------------------------------------
// fp32 [K][N] -> bf16 [N][K] tiled transpose-convert (64x64 tiles)
// ---------------------------------------------------------------------------
__global__ __launch_bounds__(256) void tconv_k(const float* __restrict__ W,
                                               ushort_t* __restrict__ WT,
                                               int K, int N) {
  __shared__ ushort_t Ls[64][72];
  const int k0 = blockIdx.y * 64, n0 = blockIdx.x * 64;
  const int t = threadIdx.x;
  const int r = t >> 4, c4 = t & 15;
#pragma unroll
  for (int i = 0; i < 4; ++i) {
    int row = r + i * 16;
    float4 v = *(const float4*)(W + (size_t)(k0 + row) * N + n0 + c4 * 4);
    Ls[row][c4 * 4 + 0] = f2bf(v.x);
    Ls[row][c4 * 4 + 1] = f2bf(v.y);
    Ls[row][c4 * 4 + 2] = f2bf(v.z);
    Ls[row][c4 * 4 + 3] = f2bf(v.w);
  }
  __syncthreads();
#pragma unroll
  for (int i = 0; i < 4; ++i) {
    int chunk = t + i * 256;
    int nr = chunk >> 4, kc = chunk & 15;
    uint2 pk;
    pk.x = (uint_t)Ls[kc * 4 + 0][nr] | ((uint_t)Ls[kc * 4 + 1][nr] << 16);
    pk.y = (uint_t)Ls[kc * 4 + 2][nr] | ((uint_t)Ls[kc * 4 + 3][nr] << 16);
    *(uint2*)(WT + (size_t)(n0 + nr) * K + k0 + kc * 4) = pk;
  }
}

// ---------------------------------------------------------------------------
// bf16 [b*S+s][128] -> bf16 [b][128][S] transpose (per-batch V^T)
// ---------------------------------------------------------------------------
__global__ __launch_bounds__(256) void vtrans_k(const ushort_t* __restrict__ Vb,
                                                ushort_t* __restrict__ Vt) {
  __shared__ ushort_t Ls[64][72];
  const int s0 = blockIdx.x * 64, d0 = blockIdx.y * 64, b = blockIdx.z;
  const int t = threadIdx.x;
#pragma unroll
  for (int i = 0; i < 2; ++i) {
    int c = t + i * 256;
    int row = c >> 3, c8 = c & 7;
    *(bf16x8*)&Ls[row][c8 * 8] =
        *(const bf16x8*)(Vb + ((size_t)b * S_ + s0 + row) * DK_ + d0 + c8 * 8);
  }
  __syncthreads();
#pragma unroll
  for (int i = 0; i < 2; ++i) {
    int c = t + i * 256;
    int dr = c >> 3, s8 = c & 7;
    uint4 pk;
    pk.x = (uint_t)Ls[s8 * 8 + 0][dr] | ((uint_t)Ls[s8 * 8 + 1][dr] << 16);
    pk.y = (uint_t)Ls[s8 * 8 + 2][dr] | ((uint_t)Ls[s8 * 8 + 3][dr] << 16);
    pk.z = (uint_t)Ls[s8 * 8 + 4][dr] | ((uint_t)Ls[s8 * 8 + 5][dr] << 16);
    pk.w = (uint_t)Ls[s8 * 8 + 6][dr] | ((uint_t)Ls[s8 * 8 + 7][dr] << 16);
    *(uint4*)(Vt + ((size_t)b * DK_ + d0 + dr) * S_ + s0 + s8 * 8) = pk;
  }
}

// ---------------------------------------------------------------------------
// bf16 MFMA GEMM: C = A[M x K] @ Bt[N x K]^T + bias, LDS-staged epilogue.
// 128x128 tile, BK=32, 4 waves (2x2), 16x16x32 MFMA, global_load_lds(16B).
// EPI: 0 = fp32 out to C1 (stride N), bias b1
//      1 = fused QKV: gcol<2048 -> RoPE+bf16 Q (C1, stride 2048, b1)
//                     2048..2175 -> RoPE+bf16 K (C2, stride 128, b2)
//                     2176..2303 -> bf16 V (C3, stride 128, b3)
// ---------------------------------------------------------------------------
template <int EPI>
__global__ __launch_bounds__(256) void gemm_mfma_k(
    const ushort_t* __restrict__ A, const ushort_t* __restrict__ Bt,
    const float* __restrict__ b1, const float* __restrict__ b2,
    const float* __restrict__ b3, const float2* __restrict__ tab,
    void* __restrict__ C1, void* __restrict__ C2, void* __restrict__ C3,
    int N, int K) {
  __shared__ ushort_t Abuf[128 * 32];
  __shared__ ushort_t Bbuf[128 * 32];
  __shared__ float Ep[32][132];

  // bijective XCD swizzle (nwg % 8 == 0 for all our grids)
  const int nwg = gridDim.x * gridDim.y;
  const int orig = blockIdx.y * gridDim.x + blockIdx.x;
  const int qq = nwg >> 3;
  const int swz = (orig & 7) * qq + (orig >> 3);
  const int bx = swz % gridDim.x, by = swz / gridDim.x;

  const int tid = threadIdx.x;
  const int lane = tid & 63;
  const int lr = lane & 15, lg = lane >> 4;
  const int w = tid >> 6, wm = w >> 1, wn = w & 1;
  const int row0 = by * 128, col0 = bx * 128;

  f32x4 acc[4][4];
#pragma unroll
  for (int i = 0; i < 4; ++i)
#pragma unroll
    for (int j = 0; j < 4; ++j) acc[i][j] = (f32x4){0.f, 0.f, 0.f, 0.f};

  for (int k0 = 0; k0 < K; k0 += 32) {
    __syncthreads();
#pragma unroll
    for (int i = 0; i < 2; ++i) {
      int c = tid + i * 256;
      int r = c >> 2, kc = c & 3;
      __builtin_amdgcn_global_load_lds(
          (const __attribute__((address_space(1))) void*)(
              A + (size_t)(row0 + r) * K + k0 + kc * 8),
          (__attribute__((address_space(3))) void*)(Abuf + c * 8), 16, 0, 0);
      __builtin_amdgcn_global_load_lds(
          (const __attribute__((address_space(1))) void*)(
              Bt + (size_t)(col0 + r) * K + k0 + kc * 8),
          (__attribute__((address_space(3))) void*)(Bbuf + c * 8), 16, 0, 0);
    }
    __syncthreads();

    bf16x8 af[4], bfr[4];
#pragma unroll
    for (int i = 0; i < 4; ++i) {
      af[i]  = *(const bf16x8*)&Abuf[(wm * 64 + i * 16 + lr) * 32 + lg * 8];
      bfr[i] = *(const bf16x8*)&Bbuf[(wn * 64 + i * 16 + lr) * 32 + lg * 8];
    }
#pragma unroll
    for (int mi = 0; mi < 4; ++mi)
#pragma unroll
      for (int ni = 0; ni < 4; ++ni)
        acc[mi][ni] = __builtin_amdgcn_mfma_f32_16x16x32_bf16(
            af[mi], bfr[ni], acc[mi][ni], 0, 0, 0);
  }

  // ---- LDS-staged epilogue: 4 rounds of [32 rows x 128 cols] fp32
  const int r5 = tid >> 3;
  const int c0 = (tid & 7) * 16;
  const int lrow = (r5 >> 4) * 64 + (r5 & 15);
  const int gcol = col0 + c0;

#pragma unroll
  for (int mi = 0; mi < 4; ++mi) {
    __syncthreads();
#pragma unroll
    for (int ni = 0; ni < 4; ++ni)
#pragma unroll
      for (int j = 0; j < 4; ++j)
        Ep[wm * 16 + lg * 4 + j][wn * 64 + ni * 16 + lr] = acc[mi][ni][j];
    __syncthreads();

    const int grow = row0 + lrow + mi * 16;
    float v[16];
#pragma unroll
    for (int q4 = 0; q4 < 4; ++q4) {
      float4 f = *(const float4*)&Ep[r5][c0 + q4 * 4];
      v[q4 * 4 + 0] = f.x; v[q4 * 4 + 1] = f.y;
      v[q4 * 4 + 2] = f.z; v[q4 * 4 + 3] = f.w;
    }

    if (EPI == 0) {
      float* Cp = (float*)C1 + (size_t)grow * N + gcol;
#pragma unroll
      for (int q4 = 0; q4 < 4; ++q4) {
        float4 bb = *(const float4*)&b1[gcol + q4 * 4];
        float4 o;
        o.x = v[q4 * 4 + 0] + bb.x; o.y = v[q4 * 4 + 1] + bb.y;
        o.z = v[q4 * 4 + 2] + bb.z; o.w = v[q4 * 4 + 3] + bb.w;
        *(float4*)(Cp + q4 * 4) = o;
      }
    } else {
      const int s = grow & (S_ - 1);
      ushort_t hs[16];
      ushort_t* Cp;
      if (gcol < DM_) {               // Q side: RoPE
        const float2* tp = tab + (size_t)s * 64 + ((gcol & 127) >> 1);
        const float* bb = b1 + gcol;
#pragma unroll
        for (int p = 0; p < 8; ++p) {
          float2 cs = tp[p];
          float v0 = v[2 * p] + bb[2 * p], v1 = v[2 * p + 1] + bb[2 * p + 1];
          hs[2 * p]     = f2bf(v0 * cs.x - v1 * cs.y);
          hs[2 * p + 1] = f2bf(v0 * cs.y + v1 * cs.x);
        }
        Cp = (ushort_t*)C1 + (size_t)grow * DM_ + gcol;
      } else if (gcol < DM_ + DK_) {  // K side: RoPE
        const int c = gcol - DM_;
        const float2* tp = tab + (size_t)s * 64 + (c >> 1);
        const float* bb = b2 + c;
#pragma unroll
        for (int p = 0; p < 8; ++p) {
          float2 cs = tp[p];
          float v0 = v[2 * p] + bb[2 * p], v1 = v[2 * p + 1] + bb[2 * p + 1];
          hs[2 * p]     = f2bf(v0 * cs.x - v1 * cs.y);
          hs[2 * p + 1] = f2bf(v0 * cs.y + v1 * cs.x);
        }
        Cp = (ushort_t*)C2 + (size_t)grow * DK_ + c;
      } else {                        // V side: plain bias
        const int c = gcol - DM_ - DK_;
#pragma unroll
        for (int kk = 0; kk < 16; ++kk) hs[kk] = f2bf(v[kk] + b3[c + kk]);
        Cp = (ushort_t*)C3 + (size_t)grow * DK_ + c;
      }
      uint4 u0, u1;
      u0.x = (uint_t)hs[0] | ((uint_t)hs[1] << 16);
      u0.y = (uint_t)hs[2] | ((uint_t)hs[3] << 16);
      u0.z = (uint_t)hs[4] | ((uint_t)hs[5] << 16);
      u0.w = (uint_t)hs[6] | ((uint_t)hs[7] << 16);
      u1.x = (uint_t)hs[8] | ((uint_t)hs[9] << 16);
      u1.y = (uint_t)hs[10] | ((uint_t)hs[11] << 16);
      u1.z = (uint_t)hs[12] | ((uint_t)hs[13] << 16);
      u1.w = (uint_t)hs[14] | ((uint_t)hs[15] << 16);
      ((uint4*)Cp)[0] = u0;
      ((uint4*)Cp)[1] = u1;
    }
  }
}

// ---------------------------------------------------------------------------
// Causal MQA flash attention v2, bf16 MFMA (16x16x32).
// Block = 4 waves = 4 HEADS sharing K/V staging (MQA); each wave owns 32
// q-rows (2 x 16 sub-tiles) of its head. KVBLK=64. V pre-transposed in global
// (Vt[b][d][s]) so V staging is coalesced + vector LDS writes.
// Swapped QK^T (S^T = K·Q^T): lane owns q=lr, kv = 16t+lg*4+r.
// PV: O^T = V^T · P^T. LDS = 53 KiB -> up to 3 blocks/CU.
// ---------------------------------------------------------------------------
__global__ __launch_bounds__(256) void attn_mfma2_k(
    const ushort_t* __restrict__ Q, const ushort_t* __restrict__ K,
    const ushort_t* __restrict__ Vt, ushort_t* __restrict__ O) {
  __shared__ ushort_t Ksh[64][136];
  __shared__ ushort_t Vsh[128][72];
  __shared__ ushort_t Psh[4][2][16][72];

  const int qt = (gridDim.x - 1) - blockIdx.x;  // big tiles first
  const int hg = blockIdx.y, b = blockIdx.z;
  const int tid = threadIdx.x;
  const int w = tid >> 6, lane = tid & 63;
  const int lr = lane & 15, lg = lane >> 4;
  const int h = hg * 4 + w;                     // wave's head
  const int q0 = qt * 32;
  const size_t bS = (size_t)b * S_;

  bf16x8 qf[2][4];
#pragma unroll
  for (int qs = 0; qs < 2; ++qs) {
    const ushort_t* qp = Q + (bS + q0 + qs * 16 + lr) * DM_ + h * DK_ + lg * 8;
#pragma unroll
    for (int kg = 0; kg < 4; ++kg) qf[qs][kg] = *(const bf16x8*)(qp + kg * 32);
  }

  f32x4 oacc[2][8];
#pragma unroll
  for (int qs = 0; qs < 2; ++qs)
#pragma unroll
    for (int i = 0; i < 8; ++i) oacc[qs][i] = (f32x4){0.f, 0.f, 0.f, 0.f};
  float m[2] = {-INFINITY, -INFINITY}, l[2] = {0.f, 0.f};

  const int ntiles = (qt >> 1) + 1;
  for (int t0 = 0; t0 < ntiles; ++t0) {
    const int kv0 = t0 * 64;
    __syncthreads();
    // ---- stage K [64 kv][128 d]
#pragma unroll
    for (int i = 0; i < 4; ++i) {
      int idx = tid + i * 256;
      int row = idx >> 4, c8 = idx & 15;
      *(bf16x8*)&Ksh[row][c8 * 8] =
          *(const bf16x8*)(K + (bS + kv0 + row) * DK_ + c8 * 8);
    }
    // ---- stage V^T [128 d][64 kv] from pre-transposed global
#pragma unroll
    for (int i = 0; i < 4; ++i) {
      int c = tid + i * 256;
      int d = c >> 3, c8 = c & 7;
      *(bf16x8*)&Vsh[d][c8 * 8] =
          *(const bf16x8*)(Vt + ((size_t)b * DK_ + d) * S_ + kv0 + c8 * 8);
    }
    __syncthreads();

    // ---- QK^T (swapped), both q-subtiles share each K fragment read
    f32x4 st[2][4];
#pragma unroll
    for (int qs = 0; qs < 2; ++qs)
#pragma unroll
      for (int t = 0; t < 4; ++t) st[qs][t] = (f32x4){0.f, 0.f, 0.f, 0.f};
#pragma unroll
    for (int t = 0; t < 4; ++t)
#pragma unroll
      for (int kg = 0; kg < 4; ++kg) {
        bf16x8 kf = *(const bf16x8*)&Ksh[t * 16 + lr][kg * 32 + lg * 8];
        st[0][t] = __builtin_amdgcn_mfma_f32_16x16x32_bf16(kf, qf[0][kg], st[0][t], 0, 0, 0);
        st[1][t] = __builtin_amdgcn_mfma_f32_16x16x32_bf16(kf, qf[1][kg], st[1][t], 0, 0, 0);
      }

    // ---- online softmax per q-subtile; P -> per-wave LDS
    const float scale = 0.08838834764831845f;  // 1/sqrt(128)
#pragma unroll
    for (int qs = 0; qs < 2; ++qs) {
      const int qg = q0 + qs * 16 + lr;
      const bool need_mask = (kv0 + 63) > (q0 + qs * 16);
      float sv[16];
      float tmax = -INFINITY;
#pragma unroll
      for (int t = 0; t < 4; ++t)
#pragma unroll
        for (int r = 0; r < 4; ++r) {
          float s = st[qs][t][r] * scale;
          if (need_mask) {
            int kvi = kv0 + t * 16 + lg * 4 + r;
            if (kvi > qg) s = -INFINITY;
          }
          sv[t * 4 + r] = s;
          tmax = fmaxf(tmax, s);
        }
      tmax = fmaxf(tmax, __shfl_xor(tmax, 16));
      tmax = fmaxf(tmax, __shfl_xor(tmax, 32));
      const float mnew = fmaxf(m[qs], tmax);
      const float corr = __expf(m[qs] - mnew);  // first tile: exp(-inf)=0
      float psum = 0.f;
      ushort_t ph[16];
#pragma unroll
      for (int i = 0; i < 16; ++i) {
        float p = __expf(sv[i] - mnew);
        psum += p;
        ph[i] = f2bf(p);
      }
      psum += __shfl_xor(psum, 16);
      psum += __shfl_xor(psum, 32);
      l[qs] = l[qs] * corr + psum;
      m[qs] = mnew;
#pragma unroll
      for (int i = 0; i < 8; ++i) {
        oacc[qs][i][0] *= corr; oacc[qs][i][1] *= corr;
        oacc[qs][i][2] *= corr; oacc[qs][i][3] *= corr;
      }
#pragma unroll
      for (int t = 0; t < 4; ++t) {
        uint2 pk;
        pk.x = (uint_t)ph[t * 4 + 0] | ((uint_t)ph[t * 4 + 1] << 16);
        pk.y = (uint_t)ph[t * 4 + 2] | ((uint_t)ph[t * 4 + 3] << 16);
        *(uint2*)&Psh[w][qs][lr][t * 16 + lg * 4] = pk;
      }
    }

    // ---- PV: O^T += V^T · P^T (V fragment shared across q-subtiles)
    bf16x8 pf[2][2];
#pragma unroll
    for (int qs = 0; qs < 2; ++qs)
#pragma unroll
      for (int kg = 0; kg < 2; ++kg)
        pf[qs][kg] = *(const bf16x8*)&Psh[w][qs][lr][kg * 32 + lg * 8];
#pragma unroll
    for (int dt = 0; dt < 8; ++dt)
#pragma unroll
      for (int kg = 0; kg < 2; ++kg) {
        bf16x8 vf = *(const bf16x8*)&Vsh[dt * 16 + lr][kg * 32 + lg * 8];
        oacc[0][dt] = __builtin_amdgcn_mfma_f32_16x16x32_bf16(vf, pf[0][kg], oacc[0][dt], 0, 0, 0);
        oacc[1][dt] = __builtin_amdgcn_mfma_f32_16x16x32_bf16(vf, pf[1][kg], oacc[1][dt], 0, 0, 0);
      }
  }

  // ---- epilogue: lane holds q = qg, d = 16dt + 4lg + reg (bf16 out)
#pragma unroll
  for (int qs = 0; qs < 2; ++qs) {
    const float invl = 1.0f / l[qs];
    const int qg = q0 + qs * 16 + lr;
    ushort_t* op = O + (bS + qg) * DM_ + h * DK_ + lg * 4;
#pragma unroll
    for (int dt = 0; dt < 8; ++dt) {
      uint2 pk;
      pk.x = (uint_t)f2bf(oacc[qs][dt][0] * invl) |
             ((uint_t)f2bf(oacc[qs][dt][1] * invl) << 16);
      pk.y = (uint_t)f2bf(oacc[qs][dt][2] * invl) |
             ((uint_t)f2bf(oacc[qs][dt][3] * invl) << 16);
      *(uint2*)(op + dt * 16) = pk;
    }
  }
}

// ---------------------------------------------------------------------------
extern "C" void kernel_launch(void* const* d_in, const int* in_sizes, int n_in,
                              void* d_out, int out_size, void* d_ws,
                              size_t ws_size, hipStream_t stream) {
  const float* x  = (const float*)d_in[0];
  const int*   tp = (const int*)d_in[1];
  const float* Wq = (const float*)d_in[2];
  const float* bq = (const float*)d_in[3];
  const float* Wk = (const float*)d_in[4];
  const float* bk = (const float*)d_in[5];
  const float* Wv = (const float*)d_in[6];
  const float* bv = (const float*)d_in[7];
  const float* Wo = (const float*)d_in[8];
  const float* bo = (const float*)d_in[9];
  float* out = (float*)d_out;

  const int NQKV = DM_ + 2 * DK_;  // 2304
  ushort_t* Xbf   = (ushort_t*)d_ws;                    // M*DM     16 MB
  ushort_t* WqkvT = Xbf + (size_t)M_ * DM_;             // 2304*DM  9.5 MB
  ushort_t* WoT   = WqkvT + (size_t)NQKV * DM_;         // DM*DM    8 MB
  ushort_t* Qbf   = WoT + (size_t)DM_ * DM_;            // M*DM     16 MB
  ushort_t* Kbf   = Qbf + (size_t)M_ * DM_;             // M*DK     1 MB
  ushort_t* Vbf   = Kbf + (size_t)M_ * DK_;             // M*DK     1 MB
  ushort_t* Vtb   = Vbf + (size_t)M_ * DK_;             // B*DK*S   1 MB
  float2*   tab   = (float2*)(Vtb + (size_t)M_ * DK_);  // S*64     1 MB
  ushort_t* ATb   = Xbf;  // alias: Xbf dead after QKV projection

  // Converts + RoPE table
  cvt_bf16_k<<<(M_ * DM_ / 4 + 255) / 256, 256, 0, stream>>>(x, Xbf, M_ * DM_);
  tconv_k<<<dim3(DM_ / 64, DM_ / 64), 256, 0, stream>>>(Wq, WqkvT, DM_, DM_);
  tconv_k<<<dim3(DK_ / 64, DM_ / 64), 256, 0, stream>>>(
      Wk, WqkvT + (size_t)DM_ * DM_, DM_, DK_);
  tconv_k<<<dim3(DK_ / 64, DM_ / 64), 256, 0, stream>>>(
      Wv, WqkvT + (size_t)(DM_ + DK_) * DM_, DM_, DK_);
  tconv_k<<<dim3(DM_ / 64, DM_ / 64), 256, 0, stream>>>(Wo, WoT, DM_, DM_);
  rope_tab_k<<<S_ * 64 / 256, 256, 0, stream>>>(tp, tab);

  // Fused QKV projection (MFMA; Q,K get RoPE; bf16 out)
  gemm_mfma_k<1><<<dim3(NQKV / 128, M_ / 128), 256, 0, stream>>>(
      Xbf, WqkvT, bq, bk, bv, tab, (void*)Qbf, (void*)Kbf, (void*)Vbf,
      NQKV, DM_);

  // V -> V^T per batch
  vtrans_k<<<dim3(S_ / 64, DK_ / 64, B_), 256, 0, stream>>>(Vbf, Vtb);

  // Causal MQA attention (4 heads/block share K/V staging)
  attn_mfma2_k<<<dim3(S_ / 32, H_ / 4, B_), 256, 0, stream>>>(
      Qbf, Kbf, Vtb, ATb);

  // Output projection (MFMA, fp32 out)
  gemm_mfma_k<0><<<dim3(DM_ / 128, M_ / 128), 256, 0, stream>>>(
      ATb, WoT, bo, nullptr, nullptr, nullptr, (void*)out, nullptr, nullptr,
      DM_, DM_);
}

// Round 6
// 235.787 us; speedup vs baseline: 12.9050x; 1.1989x over previous
//
#include <hip/hip_runtime.h>
#include <math.h>

#define B_  2
#define S_  2048
#define DM_ 2048
#define H_  16
#define DK_ 128
#define M_  (B_ * S_)

typedef __attribute__((ext_vector_type(8))) short bf16x8;
typedef __attribute__((ext_vector_type(4))) float f32x4;
typedef unsigned short ushort_t;
typedef unsigned int uint_t;

__device__ inline ushort_t f2bf(float f) {
  union { float f; uint_t u; } v; v.f = f;
  uint_t u = v.u;
  uint_t r = (u + 0x7FFFu + ((u >> 16) & 1u)) >> 16;  // RNE
  return (ushort_t)r;
}

__device__ __forceinline__ uint_t cvt_pk_bf16(float a, float b) {
  uint_t r;
  asm("v_cvt_pk_bf16_f32 %0, %1, %2" : "=v"(r) : "v"(a), "v"(b));
  return r;  // lo16 = bf16(a), hi16 = bf16(b)
}

// ---------------------------------------------------------------------------
// fp32 -> bf16 elementwise convert
// ---------------------------------------------------------------------------
__global__ void cvt_bf16_k(const float* __restrict__ in,
                           ushort_t* __restrict__ out, int n) {
  int i = (blockIdx.x * 256 + threadIdx.x) * 4;
  if (i >= n) return;
  float4 v = *(const float4*)(in + i);
  uint2 pk;
  pk.x = (uint_t)f2bf(v.x) | ((uint_t)f2bf(v.y) << 16);
  pk.y = (uint_t)f2bf(v.z) | ((uint_t)f2bf(v.w) << 16);
  *(uint2*)(out + i) = pk;
}

// ---------------------------------------------------------------------------
// RoPE table: tab[s*64 + i] = (cos, sin) of pos[s] * 10000^(-i/64)
// ---------------------------------------------------------------------------
__global__ void rope_tab_k(const int* __restrict__ pos,
                           float2* __restrict__ tab) {
  int idx = blockIdx.x * 256 + threadIdx.x;
  int s = idx >> 6, i = idx & 63;
  float ang = (float)pos[s] * exp2f((float)i * -0.2076205059304601f);
  float sn, cs;
  sincosf(ang, &sn, &cs);
  tab[idx] = make_float2(cs, sn);
}

// ---------------------------------------------------------------------------
// fp32 [K][N] -> bf16 [N][K] tiled transpose-convert (64x64 tiles)
// ---------------------------------------------------------------------------
__global__ __launch_bounds__(256) void tconv_k(const float* __restrict__ W,
                                               ushort_t* __restrict__ WT,
                                               int K, int N) {
  __shared__ ushort_t Ls[64][72];
  const int k0 = blockIdx.y * 64, n0 = blockIdx.x * 64;
  const int t = threadIdx.x;
  const int r = t >> 4, c4 = t & 15;
#pragma unroll
  for (int i = 0; i < 4; ++i) {
    int row = r + i * 16;
    float4 v = *(const float4*)(W + (size_t)(k0 + row) * N + n0 + c4 * 4);
    Ls[row][c4 * 4 + 0] = f2bf(v.x);
    Ls[row][c4 * 4 + 1] = f2bf(v.y);
    Ls[row][c4 * 4 + 2] = f2bf(v.z);
    Ls[row][c4 * 4 + 3] = f2bf(v.w);
  }
  __syncthreads();
#pragma unroll
  for (int i = 0; i < 4; ++i) {
    int chunk = t + i * 256;
    int nr = chunk >> 4, kc = chunk & 15;
    uint2 pk;
    pk.x = (uint_t)Ls[kc * 4 + 0][nr] | ((uint_t)Ls[kc * 4 + 1][nr] << 16);
    pk.y = (uint_t)Ls[kc * 4 + 2][nr] | ((uint_t)Ls[kc * 4 + 3][nr] << 16);
    *(uint2*)(WT + (size_t)(n0 + nr) * K + k0 + kc * 4) = pk;
  }
}

// ---------------------------------------------------------------------------
// bf16 [b*S+s][128] -> bf16 [b][128][S] transpose (per-batch V^T)
// ---------------------------------------------------------------------------
__global__ __launch_bounds__(256) void vtrans_k(const ushort_t* __restrict__ Vb,
                                                ushort_t* __restrict__ Vt) {
  __shared__ ushort_t Ls[64][72];
  const int s0 = blockIdx.x * 64, d0 = blockIdx.y * 64, b = blockIdx.z;
  const int t = threadIdx.x;
#pragma unroll
  for (int i = 0; i < 2; ++i) {
    int c = t + i * 256;
    int row = c >> 3, c8 = c & 7;
    *(bf16x8*)&Ls[row][c8 * 8] =
        *(const bf16x8*)(Vb + ((size_t)b * S_ + s0 + row) * DK_ + d0 + c8 * 8);
  }
  __syncthreads();
#pragma unroll
  for (int i = 0; i < 2; ++i) {
    int c = t + i * 256;
    int dr = c >> 3, s8 = c & 7;
    uint4 pk;
    pk.x = (uint_t)Ls[s8 * 8 + 0][dr] | ((uint_t)Ls[s8 * 8 + 1][dr] << 16);
    pk.y = (uint_t)Ls[s8 * 8 + 2][dr] | ((uint_t)Ls[s8 * 8 + 3][dr] << 16);
    pk.z = (uint_t)Ls[s8 * 8 + 4][dr] | ((uint_t)Ls[s8 * 8 + 5][dr] << 16);
    pk.w = (uint_t)Ls[s8 * 8 + 6][dr] | ((uint_t)Ls[s8 * 8 + 7][dr] << 16);
    *(uint4*)(Vt + ((size_t)b * DK_ + d0 + dr) * S_ + s0 + s8 * 8) = pk;
  }
}

// ---------------------------------------------------------------------------
// bf16 MFMA GEMM: C = A[M x K] @ Bt[N x K]^T + bias, LDS-staged epilogue.
// 128x128 tile, BK=32, 4 waves (2x2), 16x16x32 MFMA, global_load_lds(16B).
// EPI: 0 = fp32 out to C1 (stride N), bias b1
//      1 = fused QKV: gcol<2048 -> RoPE+bf16 Q (C1); 2048..2175 -> RoPE+bf16 K
//          (C2); 2176..2303 -> bf16 V (C3)
// ---------------------------------------------------------------------------
template <int EPI>
__global__ __launch_bounds__(256) void gemm_mfma_k(
    const ushort_t* __restrict__ A, const ushort_t* __restrict__ Bt,
    const float* __restrict__ b1, const float* __restrict__ b2,
    const float* __restrict__ b3, const float2* __restrict__ tab,
    void* __restrict__ C1, void* __restrict__ C2, void* __restrict__ C3,
    int N, int K) {
  __shared__ ushort_t Abuf[128 * 32];
  __shared__ ushort_t Bbuf[128 * 32];
  __shared__ float Ep[32][132];

  const int nwg = gridDim.x * gridDim.y;
  const int orig = blockIdx.y * gridDim.x + blockIdx.x;
  const int qq = nwg >> 3;
  const int swz = (orig & 7) * qq + (orig >> 3);
  const int bx = swz % gridDim.x, by = swz / gridDim.x;

  const int tid = threadIdx.x;
  const int lane = tid & 63;
  const int lr = lane & 15, lg = lane >> 4;
  const int w = tid >> 6, wm = w >> 1, wn = w & 1;
  const int row0 = by * 128, col0 = bx * 128;

  f32x4 acc[4][4];
#pragma unroll
  for (int i = 0; i < 4; ++i)
#pragma unroll
    for (int j = 0; j < 4; ++j) acc[i][j] = (f32x4){0.f, 0.f, 0.f, 0.f};

  for (int k0 = 0; k0 < K; k0 += 32) {
    __syncthreads();
#pragma unroll
    for (int i = 0; i < 2; ++i) {
      int c = tid + i * 256;
      int r = c >> 2, kc = c & 3;
      __builtin_amdgcn_global_load_lds(
          (const __attribute__((address_space(1))) void*)(
              A + (size_t)(row0 + r) * K + k0 + kc * 8),
          (__attribute__((address_space(3))) void*)(Abuf + c * 8), 16, 0, 0);
      __builtin_amdgcn_global_load_lds(
          (const __attribute__((address_space(1))) void*)(
              Bt + (size_t)(col0 + r) * K + k0 + kc * 8),
          (__attribute__((address_space(3))) void*)(Bbuf + c * 8), 16, 0, 0);
    }
    __syncthreads();

    bf16x8 af[4], bfr[4];
#pragma unroll
    for (int i = 0; i < 4; ++i) {
      af[i]  = *(const bf16x8*)&Abuf[(wm * 64 + i * 16 + lr) * 32 + lg * 8];
      bfr[i] = *(const bf16x8*)&Bbuf[(wn * 64 + i * 16 + lr) * 32 + lg * 8];
    }
#pragma unroll
    for (int mi = 0; mi < 4; ++mi)
#pragma unroll
      for (int ni = 0; ni < 4; ++ni)
        acc[mi][ni] = __builtin_amdgcn_mfma_f32_16x16x32_bf16(
            af[mi], bfr[ni], acc[mi][ni], 0, 0, 0);
  }

  const int r5 = tid >> 3;
  const int c0 = (tid & 7) * 16;
  const int lrow = (r5 >> 4) * 64 + (r5 & 15);
  const int gcol = col0 + c0;

#pragma unroll
  for (int mi = 0; mi < 4; ++mi) {
    __syncthreads();
#pragma unroll
    for (int ni = 0; ni < 4; ++ni)
#pragma unroll
      for (int j = 0; j < 4; ++j)
        Ep[wm * 16 + lg * 4 + j][wn * 64 + ni * 16 + lr] = acc[mi][ni][j];
    __syncthreads();

    const int grow = row0 + lrow + mi * 16;
    float v[16];
#pragma unroll
    for (int q4 = 0; q4 < 4; ++q4) {
      float4 f = *(const float4*)&Ep[r5][c0 + q4 * 4];
      v[q4 * 4 + 0] = f.x; v[q4 * 4 + 1] = f.y;
      v[q4 * 4 + 2] = f.z; v[q4 * 4 + 3] = f.w;
    }

    if (EPI == 0) {
      float* Cp = (float*)C1 + (size_t)grow * N + gcol;
#pragma unroll
      for (int q4 = 0; q4 < 4; ++q4) {
        float4 bb = *(const float4*)&b1[gcol + q4 * 4];
        float4 o;
        o.x = v[q4 * 4 + 0] + bb.x; o.y = v[q4 * 4 + 1] + bb.y;
        o.z = v[q4 * 4 + 2] + bb.z; o.w = v[q4 * 4 + 3] + bb.w;
        *(float4*)(Cp + q4 * 4) = o;
      }
    } else {
      const int s = grow & (S_ - 1);
      ushort_t hs[16];
      ushort_t* Cp;
      if (gcol < DM_) {               // Q: RoPE
        const float2* tp = tab + (size_t)s * 64 + ((gcol & 127) >> 1);
        const float* bb = b1 + gcol;
#pragma unroll
        for (int p = 0; p < 8; ++p) {
          float2 cs = tp[p];
          float v0 = v[2 * p] + bb[2 * p], v1 = v[2 * p + 1] + bb[2 * p + 1];
          hs[2 * p]     = f2bf(v0 * cs.x - v1 * cs.y);
          hs[2 * p + 1] = f2bf(v0 * cs.y + v1 * cs.x);
        }
        Cp = (ushort_t*)C1 + (size_t)grow * DM_ + gcol;
      } else if (gcol < DM_ + DK_) {  // K: RoPE
        const int c = gcol - DM_;
        const float2* tp = tab + (size_t)s * 64 + (c >> 1);
        const float* bb = b2 + c;
#pragma unroll
        for (int p = 0; p < 8; ++p) {
          float2 cs = tp[p];
          float v0 = v[2 * p] + bb[2 * p], v1 = v[2 * p + 1] + bb[2 * p + 1];
          hs[2 * p]     = f2bf(v0 * cs.x - v1 * cs.y);
          hs[2 * p + 1] = f2bf(v0 * cs.y + v1 * cs.x);
        }
        Cp = (ushort_t*)C2 + (size_t)grow * DK_ + c;
      } else {                        // V: plain bias
        const int c = gcol - DM_ - DK_;
#pragma unroll
        for (int kk = 0; kk < 16; ++kk) hs[kk] = f2bf(v[kk] + b3[c + kk]);
        Cp = (ushort_t*)C3 + (size_t)grow * DK_ + c;
      }
      uint4 u0, u1;
      u0.x = (uint_t)hs[0] | ((uint_t)hs[1] << 16);
      u0.y = (uint_t)hs[2] | ((uint_t)hs[3] << 16);
      u0.z = (uint_t)hs[4] | ((uint_t)hs[5] << 16);
      u0.w = (uint_t)hs[6] | ((uint_t)hs[7] << 16);
      u1.x = (uint_t)hs[8] | ((uint_t)hs[9] << 16);
      u1.y = (uint_t)hs[10] | ((uint_t)hs[11] << 16);
      u1.z = (uint_t)hs[12] | ((uint_t)hs[13] << 16);
      u1.w = (uint_t)hs[14] | ((uint_t)hs[15] << 16);
      ((uint4*)Cp)[0] = u0;
      ((uint4*)Cp)[1] = u1;
    }
  }
}

// ---------------------------------------------------------------------------
// Causal MQA flash attention v3: balanced complementary q-tiles.
// Block = 8 waves (512 thr): wave w -> head hg*4+(w&3), row-half w>>2.
// Every wave processes 16 rows of q-tile A=bx AND 16 rows of B=63-bx
// (32-row tiles). ntA+ntB = 33/34 for every block -> perfect balance,
// grid (32,4,2)=256 blocks = 1/CU. K/V staged once per tile for all 8 waves
// and both q-groups; K/V fragment reads shared across A/B (halves LDS BW).
// T14 async-stage: next tile's loads issued before compute.
// ---------------------------------------------------------------------------
__device__ __forceinline__ void sm_step(const f32x4* st, float& m, float& l,
                                        f32x4* oacc, int kv0, int qg,
                                        bool need_mask, int lg,
                                        ushort_t* pshrow) {
  float sv[16];
  float tmax = -INFINITY;
#pragma unroll
  for (int t = 0; t < 4; ++t)
#pragma unroll
    for (int r = 0; r < 4; ++r) {
      float s = st[t][r] * 0.08838834764831845f;  // 1/sqrt(128)
      if (need_mask && (kv0 + t * 16 + lg * 4 + r) > qg) s = -INFINITY;
      sv[t * 4 + r] = s;
      tmax = fmaxf(tmax, s);
    }
  tmax = fmaxf(tmax, __shfl_xor(tmax, 16));
  tmax = fmaxf(tmax, __shfl_xor(tmax, 32));
  if (__any(tmax > m)) {              // skip rescale when max unchanged
    float mnew = fmaxf(m, tmax);
    float corr = __expf(m - mnew);    // first tile: exp(-inf)=0
    l *= corr;
#pragma unroll
    for (int i = 0; i < 8; ++i) {
      oacc[i][0] *= corr; oacc[i][1] *= corr;
      oacc[i][2] *= corr; oacc[i][3] *= corr;
    }
    m = mnew;
  }
  float psum = 0.f;
  uint_t pk[8];
#pragma unroll
  for (int i = 0; i < 8; ++i) {
    float p0 = __expf(sv[2 * i] - m);
    float p1 = __expf(sv[2 * i + 1] - m);
    psum += p0 + p1;
    pk[i] = cvt_pk_bf16(p0, p1);
  }
  psum += __shfl_xor(psum, 16);
  psum += __shfl_xor(psum, 32);
  l += psum;
#pragma unroll
  for (int t = 0; t < 4; ++t)
    *(uint2*)&pshrow[t * 16 + lg * 4] = make_uint2(pk[2 * t], pk[2 * t + 1]);
}

__global__ __launch_bounds__(512) void attn_mfma3_k(
    const ushort_t* __restrict__ Q, const ushort_t* __restrict__ K,
    const ushort_t* __restrict__ Vt, ushort_t* __restrict__ O) {
  __shared__ ushort_t Ksh[64][136];
  __shared__ ushort_t Vsh[128][72];
  __shared__ ushort_t Psh[8][2][16][72];  // [wave][group B=0/A=1][q][kv]

  const int bx = blockIdx.x, hg = blockIdx.y, b = blockIdx.z;
  const int tid = threadIdx.x;
  const int w = tid >> 6, lane = tid & 63;
  const int lr = lane & 15, lg = lane >> 4;
  const int h = hg * 4 + (w & 3);
  const int sub = w >> 2;
  const int qtA = bx, qtB = 63 - bx;
  const int qA0 = qtA * 32 + sub * 16;   // wave's A row base
  const int qB0 = qtB * 32 + sub * 16;
  const int qA = qA0 + lr, qB = qB0 + lr;
  const int ntA = (qtA >> 1) + 1, ntB = (qtB >> 1) + 1;
  const size_t bS = (size_t)b * S_;

  bf16x8 qfA[4], qfB[4];
  {
    const ushort_t* qa = Q + (bS + qA) * DM_ + h * DK_ + lg * 8;
    const ushort_t* qb = Q + (bS + qB) * DM_ + h * DK_ + lg * 8;
#pragma unroll
    for (int kg = 0; kg < 4; ++kg) {
      qfA[kg] = *(const bf16x8*)(qa + kg * 32);
      qfB[kg] = *(const bf16x8*)(qb + kg * 32);
    }
  }

  f32x4 oA[8], oB[8];
#pragma unroll
  for (int i = 0; i < 8; ++i) {
    oA[i] = (f32x4){0.f, 0.f, 0.f, 0.f};
    oB[i] = (f32x4){0.f, 0.f, 0.f, 0.f};
  }
  float mA = -INFINITY, lA = 0.f, mB = -INFINITY, lB = 0.f;

  // async-stage registers (T14)
  bf16x8 kreg[2], vreg[2];
  const int krow = tid >> 4, kc8 = tid & 15;        // chunk tid of 1024
  const int krow2 = (tid + 512) >> 4, kc82 = tid & 15;
  const int vd = tid >> 3, vc8 = tid & 7;
  const int vd2 = (tid + 512) >> 3, vc82 = tid & 7;

#define ISSUE_LOADS(T0)                                                     \
  {                                                                         \
    const int kv_ = (T0) * 64;                                              \
    kreg[0] = *(const bf16x8*)(K + (bS + kv_ + krow) * DK_ + kc8 * 8);      \
    kreg[1] = *(const bf16x8*)(K + (bS + kv_ + krow2) * DK_ + kc82 * 8);    \
    vreg[0] = *(const bf16x8*)(Vt + ((size_t)b * DK_ + vd) * S_ + kv_ + vc8 * 8);   \
    vreg[1] = *(const bf16x8*)(Vt + ((size_t)b * DK_ + vd2) * S_ + kv_ + vc82 * 8); \
  }

  ISSUE_LOADS(0);

  for (int t0 = 0; t0 < ntB; ++t0) {
    const int kv0 = t0 * 64;
    __syncthreads();  // previous tile's LDS reads done
    *(bf16x8*)&Ksh[krow][kc8 * 8] = kreg[0];
    *(bf16x8*)&Ksh[krow2][kc82 * 8] = kreg[1];
    *(bf16x8*)&Vsh[vd][vc8 * 8] = vreg[0];
    *(bf16x8*)&Vsh[vd2][vc82 * 8] = vreg[1];
    if (t0 + 1 < ntB) ISSUE_LOADS(t0 + 1);
    __syncthreads();  // tile staged

    const bool doA = (t0 < ntA);

    // ---- QK^T (swapped): S^T = K·Q^T, K fragments shared across A/B
    f32x4 stA[4], stB[4];
#pragma unroll
    for (int t = 0; t < 4; ++t) {
      stA[t] = (f32x4){0.f, 0.f, 0.f, 0.f};
      stB[t] = (f32x4){0.f, 0.f, 0.f, 0.f};
    }
    __builtin_amdgcn_s_setprio(1);
    if (doA) {
#pragma unroll
      for (int t = 0; t < 4; ++t)
#pragma unroll
        for (int kg = 0; kg < 4; ++kg) {
          bf16x8 kf = *(const bf16x8*)&Ksh[t * 16 + lr][kg * 32 + lg * 8];
          stB[t] = __builtin_amdgcn_mfma_f32_16x16x32_bf16(kf, qfB[kg], stB[t], 0, 0, 0);
          stA[t] = __builtin_amdgcn_mfma_f32_16x16x32_bf16(kf, qfA[kg], stA[t], 0, 0, 0);
        }
    } else {
#pragma unroll
      for (int t = 0; t < 4; ++t)
#pragma unroll
        for (int kg = 0; kg < 4; ++kg) {
          bf16x8 kf = *(const bf16x8*)&Ksh[t * 16 + lr][kg * 32 + lg * 8];
          stB[t] = __builtin_amdgcn_mfma_f32_16x16x32_bf16(kf, qfB[kg], stB[t], 0, 0, 0);
        }
    }
    __builtin_amdgcn_s_setprio(0);

    // ---- online softmax (B always, A if active)
    sm_step(stB, mB, lB, oB, kv0, qB, (kv0 + 63) > qB0, lg, &Psh[w][0][lr][0]);
    if (doA)
      sm_step(stA, mA, lA, oA, kv0, qA, (kv0 + 63) > qA0, lg, &Psh[w][1][lr][0]);

    // ---- PV: O^T += V^T · P^T, V fragments shared across A/B
    bf16x8 pfB[2], pfA[2];
#pragma unroll
    for (int kg = 0; kg < 2; ++kg)
      pfB[kg] = *(const bf16x8*)&Psh[w][0][lr][kg * 32 + lg * 8];
    if (doA) {
#pragma unroll
      for (int kg = 0; kg < 2; ++kg)
        pfA[kg] = *(const bf16x8*)&Psh[w][1][lr][kg * 32 + lg * 8];
    }
    __builtin_amdgcn_s_setprio(1);
    if (doA) {
#pragma unroll
      for (int dt = 0; dt < 8; ++dt)
#pragma unroll
        for (int kg = 0; kg < 2; ++kg) {
          bf16x8 vf = *(const bf16x8*)&Vsh[dt * 16 + lr][kg * 32 + lg * 8];
          oB[dt] = __builtin_amdgcn_mfma_f32_16x16x32_bf16(vf, pfB[kg], oB[dt], 0, 0, 0);
          oA[dt] = __builtin_amdgcn_mfma_f32_16x16x32_bf16(vf, pfA[kg], oA[dt], 0, 0, 0);
        }
    } else {
#pragma unroll
      for (int dt = 0; dt < 8; ++dt)
#pragma unroll
        for (int kg = 0; kg < 2; ++kg) {
          bf16x8 vf = *(const bf16x8*)&Vsh[dt * 16 + lr][kg * 32 + lg * 8];
          oB[dt] = __builtin_amdgcn_mfma_f32_16x16x32_bf16(vf, pfB[kg], oB[dt], 0, 0, 0);
        }
    }
    __builtin_amdgcn_s_setprio(0);
  }
#undef ISSUE_LOADS

  // ---- epilogue: lane holds q-row, d = 16dt + 4lg + reg
  {
    const float invA = 1.0f / lA;
    ushort_t* op = O + (bS + qA) * DM_ + h * DK_ + lg * 4;
#pragma unroll
    for (int dt = 0; dt < 8; ++dt) {
      uint2 pk;
      pk.x = cvt_pk_bf16(oA[dt][0] * invA, oA[dt][1] * invA);
      pk.y = cvt_pk_bf16(oA[dt][2] * invA, oA[dt][3] * invA);
      *(uint2*)(op + dt * 16) = pk;
    }
  }
  {
    const float invB = 1.0f / lB;
    ushort_t* op = O + (bS + qB) * DM_ + h * DK_ + lg * 4;
#pragma unroll
    for (int dt = 0; dt < 8; ++dt) {
      uint2 pk;
      pk.x = cvt_pk_bf16(oB[dt][0] * invB, oB[dt][1] * invB);
      pk.y = cvt_pk_bf16(oB[dt][2] * invB, oB[dt][3] * invB);
      *(uint2*)(op + dt * 16) = pk;
    }
  }
}

// ---------------------------------------------------------------------------
extern "C" void kernel_launch(void* const* d_in, const int* in_sizes, int n_in,
                              void* d_out, int out_size, void* d_ws,
                              size_t ws_size, hipStream_t stream) {
  const float* x  = (const float*)d_in[0];
  const int*   tp = (const int*)d_in[1];
  const float* Wq = (const float*)d_in[2];
  const float* bq = (const float*)d_in[3];
  const float* Wk = (const float*)d_in[4];
  const float* bk = (const float*)d_in[5];
  const float* Wv = (const float*)d_in[6];
  const float* bv = (const float*)d_in[7];
  const float* Wo = (const float*)d_in[8];
  const float* bo = (const float*)d_in[9];
  float* out = (float*)d_out;

  const int NQKV = DM_ + 2 * DK_;  // 2304
  ushort_t* Xbf   = (ushort_t*)d_ws;                    // M*DM     16 MB
  ushort_t* WqkvT = Xbf + (size_t)M_ * DM_;             // 2304*DM  9.5 MB
  ushort_t* WoT   = WqkvT + (size_t)NQKV * DM_;         // DM*DM    8 MB
  ushort_t* Qbf   = WoT + (size_t)DM_ * DM_;            // M*DM     16 MB
  ushort_t* Kbf   = Qbf + (size_t)M_ * DM_;             // M*DK     1 MB
  ushort_t* Vbf   = Kbf + (size_t)M_ * DK_;             // M*DK     1 MB
  ushort_t* Vtb   = Vbf + (size_t)M_ * DK_;             // B*DK*S   1 MB
  float2*   tab   = (float2*)(Vtb + (size_t)M_ * DK_);  // S*64     1 MB
  ushort_t* ATb   = Xbf;  // alias: Xbf dead after QKV projection

  cvt_bf16_k<<<(M_ * DM_ / 4 + 255) / 256, 256, 0, stream>>>(x, Xbf, M_ * DM_);
  tconv_k<<<dim3(DM_ / 64, DM_ / 64), 256, 0, stream>>>(Wq, WqkvT, DM_, DM_);
  tconv_k<<<dim3(DK_ / 64, DM_ / 64), 256, 0, stream>>>(
      Wk, WqkvT + (size_t)DM_ * DM_, DM_, DK_);
  tconv_k<<<dim3(DK_ / 64, DM_ / 64), 256, 0, stream>>>(
      Wv, WqkvT + (size_t)(DM_ + DK_) * DM_, DM_, DK_);
  tconv_k<<<dim3(DM_ / 64, DM_ / 64), 256, 0, stream>>>(Wo, WoT, DM_, DM_);
  rope_tab_k<<<S_ * 64 / 256, 256, 0, stream>>>(tp, tab);

  // Fused QKV projection (MFMA; Q,K get RoPE; bf16 out)
  gemm_mfma_k<1><<<dim3(NQKV / 128, M_ / 128), 256, 0, stream>>>(
      Xbf, WqkvT, bq, bk, bv, tab, (void*)Qbf, (void*)Kbf, (void*)Vbf,
      NQKV, DM_);

  // V -> V^T per batch
  vtrans_k<<<dim3(S_ / 64, DK_ / 64, B_), 256, 0, stream>>>(Vbf, Vtb);

  // Causal MQA attention v3 (balanced complementary q-tiles)
  attn_mfma3_k<<<dim3(S_ / 64, H_ / 4, B_), 512, 0, stream>>>(
      Qbf, Kbf, Vtb, ATb);

  // Output projection (MFMA, fp32 out)
  gemm_mfma_k<0><<<dim3(DM_ / 128, M_ / 128), 256, 0, stream>>>(
      ATb, WoT, bo, nullptr, nullptr, nullptr, (void*)out, nullptr, nullptr,
      DM_, DM_);
}